// Round 3
// baseline (13024.268 us; speedup 1.0000x reference)
//
#include <hip/hip_runtime.h>
#include <math.h>

#define BB 64
#define NN 256
#define MM 256
#define EPSF 1e-7f

// ---------- helpers ----------

__device__ __forceinline__ void iou_diou(const float4 pb, const float4 tb,
                                         float& iou, float& diou) {
    float x1 = pb.x - pb.z * 0.5f, y1 = pb.y - pb.w * 0.5f;
    float x2 = pb.x + pb.z * 0.5f, y2 = pb.y + pb.w * 0.5f;
    float xg1 = tb.x - tb.z * 0.5f, yg1 = tb.y - tb.w * 0.5f;
    float xg2 = tb.x + tb.z * 0.5f, yg2 = tb.y + tb.w * 0.5f;
    float xi1 = fmaxf(x1, xg1), yi1 = fmaxf(y1, yg1);
    float xi2 = fminf(x2, xg2), yi2 = fminf(y2, yg2);
    float inter = fmaxf(xi2 - xi1, 0.f) * fmaxf(yi2 - yi1, 0.f);
    float uni = (x2 - x1) * (y2 - y1) + (xg2 - xg1) * (yg2 - yg1) - inter;
    iou = inter / uni;
    float iou_e = inter / (uni + EPSF);
    float xc1 = fminf(x1, xg1), yc1 = fminf(y1, yg1);
    float xc2 = fmaxf(x2, xg2), yc2 = fmaxf(y2, yg2);
    float dx = xc2 - xc1, dy = yc2 - yc1;
    float diag = dx * dx + dy * dy + EPSF;
    float ex = (x1 + x2 - xg1 - xg2) * 0.5f;
    float ey = (y1 + y2 - yg1 - yg2) * 0.5f;
    float dist = ex * ex + ey * ey;
    diou = 1.f - iou_e + dist / diag;
}

// monotone double -> u64 key, low 9 bits replaced by column index (1..256).
__device__ __forceinline__ unsigned long long dkey(double d, int j) {
    unsigned long long b = (unsigned long long)__double_as_longlong(d);
    b ^= (b >> 63) ? 0xFFFFFFFFFFFFFFFFULL : 0x8000000000000000ULL;
    return (b & ~511ULL) | (unsigned long long)j;
}
__device__ __forceinline__ double unkey(unsigned long long k) {
    unsigned long long b = k & ~511ULL;
    b ^= (b & 0x8000000000000000ULL) ? 0x8000000000000000ULL : 0xFFFFFFFFFFFFFFFFULL;
    return __longlong_as_double((long long)b);
}
__device__ __forceinline__ unsigned long long umin64(unsigned long long a, unsigned long long b) { return a < b ? a : b; }
__device__ __forceinline__ unsigned long long umax64(unsigned long long a, unsigned long long b) { return a > b ? a : b; }

#define SEL4I(s, a0, a1, a2, a3) ((s) == 0 ? (a0) : (s) == 1 ? (a1) : (s) == 2 ? (a2) : (a3))
#define SEL4D(s, a0, a1, a2, a3) ((s) == 0 ? (a0) : (s) == 1 ? (a1) : (s) == 2 ? (a2) : (a3))

// ---------- K0: per-(b,n) BCE log terms ----------
__global__ __launch_bounds__(256) void k_prep(const float* __restrict__ lp,
                                              float* __restrict__ A,
                                              float* __restrict__ C) {
    int idx = blockIdx.x * 256 + threadIdx.x;
    float x = lp[idx];
    float p = 1.f / (1.f + expf(-x));
    A[idx] = -fmaxf(logf(p), -100.f);
    C[idx] = -fmaxf(logf(1.f - p), -100.f);
}

// ---------- K1: batch-constant label_cost and l1_cost [N,M] ----------
__global__ __launch_bounds__(256) void k_nm(const float* __restrict__ A,
                                            const float* __restrict__ C,
                                            const float* __restrict__ bp,
                                            const float* __restrict__ bt,
                                            const float* __restrict__ lt,
                                            float* __restrict__ lc,
                                            float* __restrict__ l1c) {
    int n = blockIdx.x, m = threadIdx.x;
    float sl = 0.f, s1 = 0.f;
    for (int b = 0; b < BB; ++b) {
        float a = A[b * NN + n];
        float c = C[b * NN + n];
        float t = lt[b * MM + m];
        sl += t * a + (1.f - t) * c;
        float4 P = *reinterpret_cast<const float4*>(bp + ((size_t)b * NN + n) * 4);
        float4 T = *reinterpret_cast<const float4*>(bt + ((size_t)b * MM + m) * 4);
        s1 += fabsf(P.x - T.x) + fabsf(P.y - T.y) + fabsf(P.z - T.z) + fabsf(P.w - T.w);
    }
    lc[n * MM + m]  = sl * (1.f / 64.f);
    l1c[n * MM + m] = s1 * (1.f / 256.f);
}

// ---------- K2: full cost tensor [B,N,M] ----------
__global__ __launch_bounds__(256) void k_cost(const float* __restrict__ bp,
                                              const float* __restrict__ bt,
                                              const float* __restrict__ lc,
                                              const float* __restrict__ l1c,
                                              float* __restrict__ cost) {
    int bn = blockIdx.x;
    int b = bn >> 8, n = bn & 255;
    int m = threadIdx.x;
    float4 P = *reinterpret_cast<const float4*>(bp + ((size_t)bn) * 4);
    float4 T = *reinterpret_cast<const float4*>(bt + ((size_t)b * MM + m) * 4);
    float iou, diou;
    iou_diou(P, T, iou, diou);
    cost[((size_t)bn << 8) + m] = diou + lc[(n << 8) + m] + l1c[(n << 8) + m];
}

// ---------- K3: exact LAP, Jonker-Volgenant (CR + RT + 2xARR + SSP) ----------
// One wave per batch. Lane owns columns 4*lane+q+1 (1-based), q=0..3.
// Column state (v, y=p, u[y], way, minv) in registers.
__global__ __launch_bounds__(64) void k_hungarian(const float* __restrict__ cost,
                                                  int* __restrict__ cols) {
    const int b = blockIdx.x;
    const int lane = threadIdx.x;
    const float* Cm = cost + (size_t)b * NN * MM;
    const unsigned long long MAXK = 0xFFFFFFFFFFFFFFFFULL;
    const double INFD = __builtin_inf();

    __shared__ int jofrow[NN + 1];   // smallest column (1-based) claiming this row
    __shared__ int matches[NN + 1];  // # columns claiming this row in CR
    __shared__ int freeq[NN];        // free-row queue

    for (int r = lane; r <= NN; r += 64) { jofrow[r] = 0x7fffffff; matches[r] = 0; }
    __syncthreads();

    // ================= COLUMN REDUCTION =================
    float cm0 = __builtin_inff(), cm1 = cm0, cm2 = cm0, cm3 = cm0;
    int rm0 = 0, rm1 = 0, rm2 = 0, rm3 = 0;
    #pragma unroll 4
    for (int i = 0; i < NN; ++i) {
        float4 cr = *reinterpret_cast<const float4*>(Cm + (size_t)i * MM + 4 * lane);
        if (cr.x < cm0) { cm0 = cr.x; rm0 = i; }
        if (cr.y < cm1) { cm1 = cr.y; rm1 = i; }
        if (cr.z < cm2) { cm2 = cr.z; rm2 = i; }
        if (cr.w < cm3) { cm3 = cr.w; rm3 = i; }
    }
    atomicMin(&jofrow[rm0 + 1], 4 * lane + 1);
    atomicMin(&jofrow[rm1 + 1], 4 * lane + 2);
    atomicMin(&jofrow[rm2 + 1], 4 * lane + 3);
    atomicMin(&jofrow[rm3 + 1], 4 * lane + 4);
    atomicAdd(&matches[rm0 + 1], 1);
    atomicAdd(&matches[rm1 + 1], 1);
    atomicAdd(&matches[rm2 + 1], 1);
    atomicAdd(&matches[rm3 + 1], 1);
    __syncthreads();

    double vj0 = cm0, vj1 = cm1, vj2 = cm2, vj3 = cm3;   // v[j]
    double up0 = 0.0, up1 = 0.0, up2 = 0.0, up3 = 0.0;   // u[y[j]] (CS: c[y][j]-v[j])
    int pj0_ = (jofrow[rm0 + 1] == 4 * lane + 1) ? rm0 + 1 : 0;   // y[j], 0 = free
    int pj1_ = (jofrow[rm1 + 1] == 4 * lane + 2) ? rm1 + 1 : 0;
    int pj2_ = (jofrow[rm2 + 1] == 4 * lane + 3) ? rm2 + 1 : 0;
    int pj3_ = (jofrow[rm3 + 1] == 4 * lane + 4) ? rm3 + 1 : 0;
    int wy0 = 0, wy1 = 0, wy2 = 0, wy3 = 0;              // way[j]

    // ================= REDUCTION TRANSFER =================
    for (int i = 1; i <= NN; ++i) {
        if (matches[i] != 1) continue;               // uniform branch
        int j1 = jofrow[i];                          // uniform
        int o = (j1 - 1) >> 2, s = (j1 - 1) & 3;
        float4 cr = *reinterpret_cast<const float4*>(Cm + (size_t)(i - 1) * MM + 4 * lane);
        double h0 = (double)cr.x - vj0;
        double h1 = (double)cr.y - vj1;
        double h2 = (double)cr.z - vj2;
        double h3 = (double)cr.w - vj3;
        if (lane == o) {
            if (s == 0) h0 = INFD; else if (s == 1) h1 = INFD;
            else if (s == 2) h2 = INFD; else h3 = INFD;
        }
        double m = fmin(fmin(h0, h1), fmin(h2, h3));
        #pragma unroll
        for (int mmm = 1; mmm < 64; mmm <<= 1) m = fmin(m, __shfl_xor(m, mmm));
        if (lane == o) {
            if (s == 0)      { vj0 -= m; up0 += m; }
            else if (s == 1) { vj1 -= m; up1 += m; }
            else if (s == 2) { vj2 -= m; up2 += m; }
            else             { vj3 -= m; up3 += m; }
        }
    }

    // ---- build free-row queue (rows with no CR claim), deterministic order ----
    int nfree = 0;
    #pragma unroll
    for (int g = 0; g < 4; ++g) {
        int r = g * 64 + lane + 1;
        bool f = (matches[r] == 0);
        unsigned long long mk = __ballot(f);
        unsigned long long lt = (1ULL << lane) - 1ULL;
        int pos = nfree + __popcll(mk & lt);
        if (f) freeq[pos] = r;
        nfree += __popcll(mk);
    }

    // ================= AUGMENTING ROW REDUCTION (2 passes) =================
    for (int pass = 0; pass < 2; ++pass) {
        int cnt = nfree, k = 0, wn = 0;
        while (k < cnt) {
            int i = freeq[k++];                      // uniform
            int done = 0;
            for (int guard = 0; guard < 1024 && !done; ++guard) {
                float4 cr = *reinterpret_cast<const float4*>(Cm + (size_t)(i - 1) * MM + 4 * lane);
                double h0 = (double)cr.x - vj0;
                double h1 = (double)cr.y - vj1;
                double h2 = (double)cr.z - vj2;
                double h3 = (double)cr.w - vj3;
                unsigned long long kk0 = dkey(h0, 4 * lane + 1);
                unsigned long long kk1 = dkey(h1, 4 * lane + 2);
                unsigned long long kk2 = dkey(h2, 4 * lane + 3);
                unsigned long long kk3 = dkey(h3, 4 * lane + 4);
                unsigned long long a1 = umin64(kk0, kk1), b1 = umax64(kk0, kk1);
                unsigned long long a2 = umin64(kk2, kk3), b2 = umax64(kk2, kk3);
                unsigned long long K1 = umin64(a1, a2);
                unsigned long long K2 = umin64(umax64(a1, a2), umin64(b1, b2));
                #pragma unroll
                for (int mmm = 1; mmm < 64; mmm <<= 1) {
                    unsigned long long o1 = __shfl_xor(K1, mmm);
                    unsigned long long o2 = __shfl_xor(K2, mmm);
                    unsigned long long lo = umin64(K1, o1), hi = umax64(K1, o1);
                    K2 = umin64(umin64(K2, o2), hi);
                    K1 = lo;
                }
                int j1 = (int)(K1 & 511ULL), j2 = (int)(K2 & 511ULL);
                int o1i = (j1 - 1) >> 2, s1i = (j1 - 1) & 3;
                int o2i = (j2 - 1) >> 2, s2i = (j2 - 1) & 3;
                // exact values from owner lanes (keys are truncated)
                double hm1 = SEL4D(s1i, h0, h1, h2, h3);
                double hm2 = SEL4D(s2i, h0, h1, h2, h3);
                double uminx = __shfl(hm1, o1i);
                double usubx = __shfl(hm2, o2i);
                int pv1 = SEL4I(s1i, pj0_, pj1_, pj2_, pj3_);
                int i0 = __shfl(pv1, o1i);
                bool strict = (uminx < usubx);
                int ja = j1, oa = o1i, sa = s1i;
                if (strict) {
                    if (lane == o1i) {
                        double d = usubx - uminx;
                        if (s1i == 0) vj0 -= d; else if (s1i == 1) vj1 -= d;
                        else if (s1i == 2) vj2 -= d; else vj3 -= d;
                    }
                } else if (i0 > 0) {
                    ja = j2; oa = o2i; sa = s2i;
                    int pv2 = SEL4I(s2i, pj0_, pj1_, pj2_, pj3_);
                    i0 = __shfl(pv2, o2i);
                }
                if (lane == oa) {                     // y[ja]=i; u[y]=usubx (CS)
                    if (sa == 0)      { pj0_ = i; up0 = usubx; }
                    else if (sa == 1) { pj1_ = i; up1 = usubx; }
                    else if (sa == 2) { pj2_ = i; up2 = usubx; }
                    else              { pj3_ = i; up3 = usubx; }
                }
                if (i0 > 0 && strict) {
                    i = i0;                           // immediate reprocess
                } else {
                    if (i0 > 0) { if (lane == 0) freeq[wn] = i0; wn++; }
                    done = 1;
                }
            }
            if (!done) { if (lane == 0) freeq[wn] = i; wn++; }   // safety valve
        }
        nfree = wn;
    }

    // ================= SSP (Dijkstra) for remaining free rows =================
    for (int fi = 0; fi < nfree; ++fi) {
        int i = freeq[fi];                            // uniform

        double u_i = 0.0;
        double mv0 = INFD, mv1 = INFD, mv2 = INFD, mv3 = INFD;
        int used4 = 0;
        int j0 = 0;
        int i0 = i;
        double ui0 = 0.0;

        for (int it = 0; it <= NN; ++it) {
            float4 cr = *reinterpret_cast<const float4*>(Cm + (size_t)(i0 - 1) * MM + 4 * lane);
            if (!(used4 & 1)) { double cur = ((double)cr.x - ui0) - vj0; if (cur < mv0) { mv0 = cur; wy0 = j0; } }
            if (!(used4 & 2)) { double cur = ((double)cr.y - ui0) - vj1; if (cur < mv1) { mv1 = cur; wy1 = j0; } }
            if (!(used4 & 4)) { double cur = ((double)cr.z - ui0) - vj2; if (cur < mv2) { mv2 = cur; wy2 = j0; } }
            if (!(used4 & 8)) { double cur = ((double)cr.w - ui0) - vj3; if (cur < mv3) { mv3 = cur; wy3 = j0; } }

            unsigned long long k0 = (used4 & 1) ? MAXK : dkey(mv0, 4 * lane + 1);
            unsigned long long k1 = (used4 & 2) ? MAXK : dkey(mv1, 4 * lane + 2);
            unsigned long long k2 = (used4 & 4) ? MAXK : dkey(mv2, 4 * lane + 3);
            unsigned long long k3 = (used4 & 8) ? MAXK : dkey(mv3, 4 * lane + 4);

            unsigned long long ka; int pa; double ua;
            if (k1 < k0) { ka = k1; pa = pj1_; ua = up1; } else { ka = k0; pa = pj0_; ua = up0; }
            unsigned long long kb; int pb; double ub;
            if (k3 < k2) { kb = k3; pb = pj3_; ub = up3; } else { kb = k2; pb = pj2_; ub = up2; }
            if (kb < ka) { ka = kb; pa = pb; ua = ub; }

            #pragma unroll
            for (int mmm = 1; mmm < 64; mmm <<= 1) {
                unsigned long long ok = __shfl_xor(ka, mmm);
                int op = __shfl_xor(pa, mmm);
                double ou = __shfl_xor(ua, mmm);
                if (ok < ka) { ka = ok; pa = op; ua = ou; }
            }
            double delta = unkey(ka);
            int j1 = (int)(ka & 511ULL);

            u_i += delta;
            if (used4 & 1) { up0 += delta; vj0 -= delta; } else { mv0 -= delta; }
            if (used4 & 2) { up1 += delta; vj1 -= delta; } else { mv1 -= delta; }
            if (used4 & 4) { up2 += delta; vj2 -= delta; } else { mv2 -= delta; }
            if (used4 & 8) { up3 += delta; vj3 -= delta; } else { mv3 -= delta; }

            j0 = j1;
            if (pa == 0) break;
            int ci = j1 - 1;
            if ((ci >> 2) == lane) used4 |= 1 << (ci & 3);
            i0 = pa;
            ui0 = ua;
        }

        // augment along way pointers
        int jj = j0;
        while (jj) {
            int o = (jj - 1) >> 2, s = (jj - 1) & 3;
            int wv = SEL4I(s, wy0, wy1, wy2, wy3);
            int jn = __shfl(wv, o);
            int pn; double un;
            if (jn == 0) { pn = i; un = u_i; }
            else {
                int o2 = (jn - 1) >> 2, s2 = (jn - 1) & 3;
                int pv = SEL4I(s2, pj0_, pj1_, pj2_, pj3_);
                double uv = SEL4D(s2, up0, up1, up2, up3);
                pn = __shfl(pv, o2);
                un = __shfl(uv, o2);
            }
            if (lane == o) {
                if (s == 0)      { pj0_ = pn; up0 = un; }
                else if (s == 1) { pj1_ = pn; up1 = un; }
                else if (s == 2) { pj2_ = pn; up2 = un; }
                else             { pj3_ = pn; up3 = un; }
            }
            jj = jn;
        }
    }

    // col_of_row: cols[y[j]-1] = j-1
    cols[b * NN + (pj0_ - 1)] = 4 * lane + 0;
    cols[b * NN + (pj1_ - 1)] = 4 * lane + 1;
    cols[b * NN + (pj2_ - 1)] = 4 * lane + 2;
    cols[b * NN + (pj3_ - 1)] = 4 * lane + 3;
}

// ---------- K4: matched losses, per-block (batch) partial sums ----------
__global__ __launch_bounds__(256) void k_loss(const float* __restrict__ lp,
                                              const float* __restrict__ bp,
                                              const float* __restrict__ lt,
                                              const float* __restrict__ bt,
                                              const int* __restrict__ cols,
                                              float* __restrict__ partials) {
    int b = blockIdx.x, n = threadIdx.x;
    int col = cols[b * NN + n];
    float x = lp[b * NN + n];
    float pp = 1.f / (1.f + expf(-x));
    float t = lt[b * MM + col];
    float4 P = *reinterpret_cast<const float4*>(bp + ((size_t)b * NN + n) * 4);
    float4 T = *reinterpret_cast<const float4*>(bt + ((size_t)b * MM + col) * 4);
    float w = (t == 1.f) ? 1.f : 0.f;
    float iou, diou;
    iou_diou(P, T, iou, diou);
    float bce = -(t * fmaxf(logf(pp), -100.f) + (1.f - t) * fmaxf(logf(1.f - pp), -100.f));
    float l1 = fabsf(P.x - T.x) + fabsf(P.y - T.y) + fabsf(P.z - T.z) + fabsf(P.w - T.w);

    float v0 = w, v1 = diou * w, v2 = iou * w, v3 = bce, v4 = l1 * w;
    #pragma unroll
    for (int mm = 1; mm < 64; mm <<= 1) {
        v0 += __shfl_xor(v0, mm); v1 += __shfl_xor(v1, mm);
        v2 += __shfl_xor(v2, mm); v3 += __shfl_xor(v3, mm);
        v4 += __shfl_xor(v4, mm);
    }
    __shared__ float red[4][5];
    int wid = n >> 6, lane = n & 63;
    if (lane == 0) { red[wid][0] = v0; red[wid][1] = v1; red[wid][2] = v2; red[wid][3] = v3; red[wid][4] = v4; }
    __syncthreads();
    if (n == 0) {
        float s0 = red[0][0] + red[1][0] + red[2][0] + red[3][0];
        float s1 = red[0][1] + red[1][1] + red[2][1] + red[3][1];
        float s2 = red[0][2] + red[1][2] + red[2][2] + red[3][2];
        float s3 = red[0][3] + red[1][3] + red[2][3] + red[3][3];
        float s4 = red[0][4] + red[1][4] + red[2][4] + red[3][4];
        partials[b * 8 + 0] = s0; partials[b * 8 + 1] = s1; partials[b * 8 + 2] = s2;
        partials[b * 8 + 3] = s3; partials[b * 8 + 4] = s4;
    }
}

// ---------- K5: final scalar combine ----------
__global__ __launch_bounds__(64) void k_final(const float* __restrict__ partials,
                                              float* __restrict__ out) {
    int t = threadIdx.x;
    float v0 = partials[t * 8 + 0], v1 = partials[t * 8 + 1], v2 = partials[t * 8 + 2];
    float v3 = partials[t * 8 + 3], v4 = partials[t * 8 + 4];
    #pragma unroll
    for (int mm = 1; mm < 64; mm <<= 1) {
        v0 += __shfl_xor(v0, mm); v1 += __shfl_xor(v1, mm);
        v2 += __shfl_xor(v2, mm); v3 += __shfl_xor(v3, mm);
        v4 += __shfl_xor(v4, mm);
    }
    if (t == 0) {
        float wsum = v0;
        float diou_loss = v1 / wsum;
        float iou = v2 / wsum;
        float label_loss = v3 * (1.f / (64.f * 256.f));
        float bbox_loss = v4 / (wsum * 4.f);
        out[0] = diou_loss + label_loss + bbox_loss;
        out[1] = iou;
    }
}

extern "C" void kernel_launch(void* const* d_in, const int* in_sizes, int n_in,
                              void* d_out, int out_size, void* d_ws, size_t ws_size,
                              hipStream_t stream) {
    const float* labels_pred   = (const float*)d_in[0];
    const float* bbox_pred     = (const float*)d_in[1];
    const float* labels_target = (const float*)d_in[2];
    const float* bbox_target   = (const float*)d_in[3];
    float* out = (float*)d_out;

    float* A    = (float*)d_ws;
    float* C    = A + BB * NN;
    float* lc   = C + BB * NN;
    float* l1c  = lc + NN * MM;
    float* cost = l1c + NN * MM;
    int*   cols = (int*)(cost + (size_t)BB * NN * MM);
    float* partials = (float*)(cols + BB * NN);

    k_prep<<<BB * NN / 256, 256, 0, stream>>>(labels_pred, A, C);
    k_nm<<<NN, MM, 0, stream>>>(A, C, bbox_pred, bbox_target, labels_target, lc, l1c);
    k_cost<<<BB * NN, MM, 0, stream>>>(bbox_pred, bbox_target, lc, l1c, cost);
    k_hungarian<<<BB, 64, 0, stream>>>(cost, cols);
    k_loss<<<BB, NN, 0, stream>>>(labels_pred, bbox_pred, labels_target, bbox_target, cols, partials);
    k_final<<<1, 64, 0, stream>>>(partials, out);
}

// Round 4
// 3415.871 us; speedup vs baseline: 3.8129x; 3.8129x over previous
//
#include <hip/hip_runtime.h>
#include <math.h>

#define BB 64
#define NN 256
#define MM 256
#define EPSF 1e-7f

// ---------- helpers ----------

__device__ __forceinline__ void iou_diou(const float4 pb, const float4 tb,
                                         float& iou, float& diou) {
    float x1 = pb.x - pb.z * 0.5f, y1 = pb.y - pb.w * 0.5f;
    float x2 = pb.x + pb.z * 0.5f, y2 = pb.y + pb.w * 0.5f;
    float xg1 = tb.x - tb.z * 0.5f, yg1 = tb.y - tb.w * 0.5f;
    float xg2 = tb.x + tb.z * 0.5f, yg2 = tb.y + tb.w * 0.5f;
    float xi1 = fmaxf(x1, xg1), yi1 = fmaxf(y1, yg1);
    float xi2 = fminf(x2, xg2), yi2 = fminf(y2, yg2);
    float inter = fmaxf(xi2 - xi1, 0.f) * fmaxf(yi2 - yi1, 0.f);
    float uni = (x2 - x1) * (y2 - y1) + (xg2 - xg1) * (yg2 - yg1) - inter;
    iou = inter / uni;
    float iou_e = inter / (uni + EPSF);
    float xc1 = fminf(x1, xg1), yc1 = fminf(y1, yg1);
    float xc2 = fmaxf(x2, xg2), yc2 = fmaxf(y2, yg2);
    float dx = xc2 - xc1, dy = yc2 - yc1;
    float diag = dx * dx + dy * dy + EPSF;
    float ex = (x1 + x2 - xg1 - xg2) * 0.5f;
    float ey = (y1 + y2 - yg1 - yg2) * 0.5f;
    float dist = ex * ex + ey * ey;
    diou = 1.f - iou_e + dist / diag;
}

// monotone double -> u64 key, low 9 bits replaced by column index (1..256).
__device__ __forceinline__ unsigned long long dkey(double d, int j) {
    unsigned long long b = (unsigned long long)__double_as_longlong(d);
    b ^= (b >> 63) ? 0xFFFFFFFFFFFFFFFFULL : 0x8000000000000000ULL;
    return (b & ~511ULL) | (unsigned long long)j;
}
__device__ __forceinline__ double unkey(unsigned long long k) {
    unsigned long long b = k & ~511ULL;
    b ^= (b & 0x8000000000000000ULL) ? 0x8000000000000000ULL : 0xFFFFFFFFFFFFFFFFULL;
    return __longlong_as_double((long long)b);
}

#define SEL4I(s, a0, a1, a2, a3) ((s) == 0 ? (a0) : (s) == 1 ? (a1) : (s) == 2 ? (a2) : (a3))
#define SEL4D(s, a0, a1, a2, a3) ((s) == 0 ? (a0) : (s) == 1 ? (a1) : (s) == 2 ? (a2) : (a3))

// DPP butterfly step on (ka:u64 key, pa:i32 payload). CTRL must be a literal.
// quad_perm xor1 = 0xB1, quad_perm xor2 = 0x4E, row_half_mirror = 0x141,
// row_mirror = 0x140 — valid min-reduce pairings for levels 2/4/8/16.
#define BFLY_DPP(CTRL)                                                                    \
    do {                                                                                  \
        unsigned int lo_ = (unsigned int)ka, hi_ = (unsigned int)(ka >> 32);              \
        unsigned int nlo_ = (unsigned int)__builtin_amdgcn_update_dpp(0, (int)lo_, CTRL, 0xF, 0xF, true); \
        unsigned int nhi_ = (unsigned int)__builtin_amdgcn_update_dpp(0, (int)hi_, CTRL, 0xF, 0xF, true); \
        int npa_ = __builtin_amdgcn_update_dpp(0, pa, CTRL, 0xF, 0xF, true);              \
        unsigned long long ok_ = ((unsigned long long)nhi_ << 32) | nlo_;                 \
        if (ok_ < ka) { ka = ok_; pa = npa_; }                                            \
    } while (0)

// ---------- K0: per-(b,n) BCE log terms ----------
__global__ __launch_bounds__(256) void k_prep(const float* __restrict__ lp,
                                              float* __restrict__ A,
                                              float* __restrict__ C) {
    int idx = blockIdx.x * 256 + threadIdx.x;
    float x = lp[idx];
    float p = 1.f / (1.f + expf(-x));
    A[idx] = -fmaxf(logf(p), -100.f);
    C[idx] = -fmaxf(logf(1.f - p), -100.f);
}

// ---------- K1: batch-constant label_cost and l1_cost [N,M] ----------
__global__ __launch_bounds__(256) void k_nm(const float* __restrict__ A,
                                            const float* __restrict__ C,
                                            const float* __restrict__ bp,
                                            const float* __restrict__ bt,
                                            const float* __restrict__ lt,
                                            float* __restrict__ lc,
                                            float* __restrict__ l1c) {
    int n = blockIdx.x, m = threadIdx.x;
    float sl = 0.f, s1 = 0.f;
    for (int b = 0; b < BB; ++b) {
        float a = A[b * NN + n];
        float c = C[b * NN + n];
        float t = lt[b * MM + m];
        sl += t * a + (1.f - t) * c;
        float4 P = *reinterpret_cast<const float4*>(bp + ((size_t)b * NN + n) * 4);
        float4 T = *reinterpret_cast<const float4*>(bt + ((size_t)b * MM + m) * 4);
        s1 += fabsf(P.x - T.x) + fabsf(P.y - T.y) + fabsf(P.z - T.z) + fabsf(P.w - T.w);
    }
    lc[n * MM + m]  = sl * (1.f / 64.f);
    l1c[n * MM + m] = s1 * (1.f / 256.f);
}

// ---------- K2: full cost tensor [B,N,M] ----------
__global__ __launch_bounds__(256) void k_cost(const float* __restrict__ bp,
                                              const float* __restrict__ bt,
                                              const float* __restrict__ lc,
                                              const float* __restrict__ l1c,
                                              float* __restrict__ cost) {
    int bn = blockIdx.x;
    int b = bn >> 8, n = bn & 255;
    int m = threadIdx.x;
    float4 P = *reinterpret_cast<const float4*>(bp + ((size_t)bn) * 4);
    float4 T = *reinterpret_cast<const float4*>(bt + ((size_t)b * MM + m) * 4);
    float iou, diou;
    iou_diou(P, T, iou, diou);
    cost[((size_t)bn << 8) + m] = diou + lc[(n << 8) + m] + l1c[(n << 8) + m];
}

// ---------- K3: exact LAP (CR + greedy + SSP), one wave per batch ----------
// Lane owns columns 4*lane+q+1 (1-based), q=0..3. Column state in registers;
// argmin via DPP(4 steps)+shfl(2 steps) butterfly on packed u64 key + i32 row
// payload; winner's u fetched post-reduce (hides under the next row load).
__global__ __launch_bounds__(64) void k_hungarian(const float* __restrict__ cost,
                                                  int* __restrict__ cols) {
    const int b = blockIdx.x;
    const int lane = threadIdx.x;
    const float* Cm = cost + (size_t)b * NN * MM;
    const unsigned long long MAXK = 0xFFFFFFFFFFFFFFFFULL;
    const double INFD = __builtin_inf();

    __shared__ int jofrow[NN + 1];   // smallest column (1-based) whose argmin is this row
    for (int r = lane; r <= NN; r += 64) jofrow[r] = 0x7fffffff;
    __syncthreads();

    // ---- column reduction: v[j] = min_i c[i][j], remember argmin row ----
    float cm0 = __builtin_inff(), cm1 = cm0, cm2 = cm0, cm3 = cm0;
    int rm0 = 0, rm1 = 0, rm2 = 0, rm3 = 0;
    #pragma unroll 4
    for (int i = 0; i < NN; ++i) {
        float4 cr = *reinterpret_cast<const float4*>(Cm + (size_t)i * MM + 4 * lane);
        if (cr.x < cm0) { cm0 = cr.x; rm0 = i; }
        if (cr.y < cm1) { cm1 = cr.y; rm1 = i; }
        if (cr.z < cm2) { cm2 = cr.z; rm2 = i; }
        if (cr.w < cm3) { cm3 = cr.w; rm3 = i; }
    }
    atomicMin(&jofrow[rm0 + 1], 4 * lane + 1);
    atomicMin(&jofrow[rm1 + 1], 4 * lane + 2);
    atomicMin(&jofrow[rm2 + 1], 4 * lane + 3);
    atomicMin(&jofrow[rm3 + 1], 4 * lane + 4);
    __syncthreads();

    // ---- greedy pre-assignment + register state init ----
    double vj0 = cm0, vj1 = cm1, vj2 = cm2, vj3 = cm3;   // v[j]
    double up0 = 0.0, up1 = 0.0, up2 = 0.0, up3 = 0.0;   // u[p[j]]
    int pj0_ = (jofrow[rm0 + 1] == 4 * lane + 1) ? rm0 + 1 : 0;
    int pj1_ = (jofrow[rm1 + 1] == 4 * lane + 2) ? rm1 + 1 : 0;
    int pj2_ = (jofrow[rm2 + 1] == 4 * lane + 3) ? rm2 + 1 : 0;
    int pj3_ = (jofrow[rm3 + 1] == 4 * lane + 4) ? rm3 + 1 : 0;
    int wy0 = 0, wy1 = 0, wy2 = 0, wy3 = 0;              // way[j]

    // assigned-row bitmasks (wave-uniform)
    unsigned long long am0 = __ballot(jofrow[1 + lane]       != 0x7fffffff);
    unsigned long long am1 = __ballot(jofrow[1 + 64 + lane]  != 0x7fffffff);
    unsigned long long am2 = __ballot(jofrow[1 + 128 + lane] != 0x7fffffff);
    unsigned long long am3 = __ballot(jofrow[1 + 192 + lane] != 0x7fffffff);

    for (int i = 1; i <= NN; ++i) {
        unsigned long long am = (i <= 64) ? am0 : (i <= 128) ? am1 : (i <= 192) ? am2 : am3;
        if ((am >> ((i - 1) & 63)) & 1ULL) continue;   // row pre-assigned

        double u_i = 0.0;
        double mv0 = INFD, mv1 = INFD, mv2 = INFD, mv3 = INFD;
        int used4 = 0;
        int j0 = 0;
        int i0 = i;
        double ui0 = 0.0;

        for (int it = 0; it <= NN; ++it) {
            float4 cr = *reinterpret_cast<const float4*>(Cm + (size_t)(i0 - 1) * MM + 4 * lane);
            if (!(used4 & 1)) { double cur = ((double)cr.x - ui0) - vj0; if (cur < mv0) { mv0 = cur; wy0 = j0; } }
            if (!(used4 & 2)) { double cur = ((double)cr.y - ui0) - vj1; if (cur < mv1) { mv1 = cur; wy1 = j0; } }
            if (!(used4 & 4)) { double cur = ((double)cr.z - ui0) - vj2; if (cur < mv2) { mv2 = cur; wy2 = j0; } }
            if (!(used4 & 8)) { double cur = ((double)cr.w - ui0) - vj3; if (cur < mv3) { mv3 = cur; wy3 = j0; } }

            unsigned long long k0 = (used4 & 1) ? MAXK : dkey(mv0, 4 * lane + 1);
            unsigned long long k1 = (used4 & 2) ? MAXK : dkey(mv1, 4 * lane + 2);
            unsigned long long k2 = (used4 & 4) ? MAXK : dkey(mv2, 4 * lane + 3);
            unsigned long long k3 = (used4 & 8) ? MAXK : dkey(mv3, 4 * lane + 4);

            // local payload reduce (value-then-smallest-j via key low bits)
            unsigned long long ka; int pa;
            if (k1 < k0) { ka = k1; pa = pj1_; } else { ka = k0; pa = pj0_; }
            unsigned long long kb; int pb;
            if (k3 < k2) { kb = k3; pb = pj3_; } else { kb = k2; pb = pj2_; }
            if (kb < ka) { ka = kb; pa = pb; }

            // 64-lane butterfly min: 4 DPP steps (VALU) + 2 cross-row shfl steps
            BFLY_DPP(0xB1);    // xor1  (quad_perm [1,0,3,2])
            BFLY_DPP(0x4E);    // xor2  (quad_perm [2,3,0,1])
            BFLY_DPP(0x141);   // pair across quads (row_half_mirror)
            BFLY_DPP(0x140);   // pair across 8-halves (row_mirror)
            {
                unsigned long long ok = __shfl_xor(ka, 16);
                int op = __shfl_xor(pa, 16);
                if (ok < ka) { ka = ok; pa = op; }
            }
            {
                unsigned long long ok = __shfl_xor(ka, 32);
                int op = __shfl_xor(pa, 32);
                if (ok < ka) { ka = ok; pa = op; }
            }

            double delta = unkey(ka);
            int j1 = (int)(ka & 511ULL);

            // winner's u[p[j1]] fetched post-reduce; consumed only after the
            // next row load returns, so this shfl hides under the load.
            int o1 = (j1 - 1) >> 2, s1 = (j1 - 1) & 3;
            double uvq = SEL4D(s1, up0, up1, up2, up3);
            double ua = __shfl(uvq, o1);

            u_i += delta;
            if (used4 & 1) { up0 += delta; vj0 -= delta; } else { mv0 -= delta; }
            if (used4 & 2) { up1 += delta; vj1 -= delta; } else { mv1 -= delta; }
            if (used4 & 4) { up2 += delta; vj2 -= delta; } else { mv2 -= delta; }
            if (used4 & 8) { up3 += delta; vj3 -= delta; } else { mv3 -= delta; }

            j0 = j1;
            if (pa == 0) break;            // reached a free column
            int ci = j1 - 1;
            if ((ci >> 2) == lane) used4 |= 1 << (ci & 3);
            i0 = pa;
            ui0 = ua;
        }

        // ---- augment along way pointers (jj uniform; cross-lane via shfl) ----
        int jj = j0;
        while (jj) {
            int o = (jj - 1) >> 2, s = (jj - 1) & 3;
            int wv = SEL4I(s, wy0, wy1, wy2, wy3);
            int jn = __shfl(wv, o);
            int pn; double un;
            if (jn == 0) { pn = i; un = u_i; }
            else {
                int o2 = (jn - 1) >> 2, s2 = (jn - 1) & 3;
                int pv = SEL4I(s2, pj0_, pj1_, pj2_, pj3_);
                double uv = SEL4D(s2, up0, up1, up2, up3);
                pn = __shfl(pv, o2);
                un = __shfl(uv, o2);
            }
            if (lane == o) {
                if (s == 0)      { pj0_ = pn; up0 = un; }
                else if (s == 1) { pj1_ = pn; up1 = un; }
                else if (s == 2) { pj2_ = pn; up2 = un; }
                else             { pj3_ = pn; up3 = un; }
            }
            jj = jn;
        }
    }

    // col_of_row: cols[p[j]-1] = j-1
    cols[b * NN + (pj0_ - 1)] = 4 * lane + 0;
    cols[b * NN + (pj1_ - 1)] = 4 * lane + 1;
    cols[b * NN + (pj2_ - 1)] = 4 * lane + 2;
    cols[b * NN + (pj3_ - 1)] = 4 * lane + 3;
}

// ---------- K4: matched losses, per-block (batch) partial sums ----------
__global__ __launch_bounds__(256) void k_loss(const float* __restrict__ lp,
                                              const float* __restrict__ bp,
                                              const float* __restrict__ lt,
                                              const float* __restrict__ bt,
                                              const int* __restrict__ cols,
                                              float* __restrict__ partials) {
    int b = blockIdx.x, n = threadIdx.x;
    int col = cols[b * NN + n];
    float x = lp[b * NN + n];
    float pp = 1.f / (1.f + expf(-x));
    float t = lt[b * MM + col];
    float4 P = *reinterpret_cast<const float4*>(bp + ((size_t)b * NN + n) * 4);
    float4 T = *reinterpret_cast<const float4*>(bt + ((size_t)b * MM + col) * 4);
    float w = (t == 1.f) ? 1.f : 0.f;
    float iou, diou;
    iou_diou(P, T, iou, diou);
    float bce = -(t * fmaxf(logf(pp), -100.f) + (1.f - t) * fmaxf(logf(1.f - pp), -100.f));
    float l1 = fabsf(P.x - T.x) + fabsf(P.y - T.y) + fabsf(P.z - T.z) + fabsf(P.w - T.w);

    float v0 = w, v1 = diou * w, v2 = iou * w, v3 = bce, v4 = l1 * w;
    #pragma unroll
    for (int mm = 1; mm < 64; mm <<= 1) {
        v0 += __shfl_xor(v0, mm); v1 += __shfl_xor(v1, mm);
        v2 += __shfl_xor(v2, mm); v3 += __shfl_xor(v3, mm);
        v4 += __shfl_xor(v4, mm);
    }
    __shared__ float red[4][5];
    int wid = n >> 6, lane = n & 63;
    if (lane == 0) { red[wid][0] = v0; red[wid][1] = v1; red[wid][2] = v2; red[wid][3] = v3; red[wid][4] = v4; }
    __syncthreads();
    if (n == 0) {
        float s0 = red[0][0] + red[1][0] + red[2][0] + red[3][0];
        float s1 = red[0][1] + red[1][1] + red[2][1] + red[3][1];
        float s2 = red[0][2] + red[1][2] + red[2][2] + red[3][2];
        float s3 = red[0][3] + red[1][3] + red[2][3] + red[3][3];
        float s4 = red[0][4] + red[1][4] + red[2][4] + red[3][4];
        partials[b * 8 + 0] = s0; partials[b * 8 + 1] = s1; partials[b * 8 + 2] = s2;
        partials[b * 8 + 3] = s3; partials[b * 8 + 4] = s4;
    }
}

// ---------- K5: final scalar combine ----------
__global__ __launch_bounds__(64) void k_final(const float* __restrict__ partials,
                                              float* __restrict__ out) {
    int t = threadIdx.x;
    float v0 = partials[t * 8 + 0], v1 = partials[t * 8 + 1], v2 = partials[t * 8 + 2];
    float v3 = partials[t * 8 + 3], v4 = partials[t * 8 + 4];
    #pragma unroll
    for (int mm = 1; mm < 64; mm <<= 1) {
        v0 += __shfl_xor(v0, mm); v1 += __shfl_xor(v1, mm);
        v2 += __shfl_xor(v2, mm); v3 += __shfl_xor(v3, mm);
        v4 += __shfl_xor(v4, mm);
    }
    if (t == 0) {
        float wsum = v0;
        float diou_loss = v1 / wsum;
        float iou = v2 / wsum;
        float label_loss = v3 * (1.f / (64.f * 256.f));
        float bbox_loss = v4 / (wsum * 4.f);
        out[0] = diou_loss + label_loss + bbox_loss;
        out[1] = iou;
    }
}

extern "C" void kernel_launch(void* const* d_in, const int* in_sizes, int n_in,
                              void* d_out, int out_size, void* d_ws, size_t ws_size,
                              hipStream_t stream) {
    const float* labels_pred   = (const float*)d_in[0];
    const float* bbox_pred     = (const float*)d_in[1];
    const float* labels_target = (const float*)d_in[2];
    const float* bbox_target   = (const float*)d_in[3];
    float* out = (float*)d_out;

    float* A    = (float*)d_ws;
    float* C    = A + BB * NN;
    float* lc   = C + BB * NN;
    float* l1c  = lc + NN * MM;
    float* cost = l1c + NN * MM;
    int*   cols = (int*)(cost + (size_t)BB * NN * MM);
    float* partials = (float*)(cols + BB * NN);

    k_prep<<<BB * NN / 256, 256, 0, stream>>>(labels_pred, A, C);
    k_nm<<<NN, MM, 0, stream>>>(A, C, bbox_pred, bbox_target, labels_target, lc, l1c);
    k_cost<<<BB * NN, MM, 0, stream>>>(bbox_pred, bbox_target, lc, l1c, cost);
    k_hungarian<<<BB, 64, 0, stream>>>(cost, cols);
    k_loss<<<BB, NN, 0, stream>>>(labels_pred, bbox_pred, labels_target, bbox_target, cols, partials);
    k_final<<<1, 64, 0, stream>>>(partials, out);
}

// Round 5
// 3206.033 us; speedup vs baseline: 4.0624x; 1.0655x over previous
//
#include <hip/hip_runtime.h>
#include <math.h>

#define BB 64
#define NN 256
#define MM 256
#define EPSF 1e-7f
#define ROWS_LDS 144   // 144 KB row cache; + jofrow ~1 KB << 160 KB gfx950 LDS

// ---------- helpers ----------

__device__ __forceinline__ void iou_diou(const float4 pb, const float4 tb,
                                         float& iou, float& diou) {
    float x1 = pb.x - pb.z * 0.5f, y1 = pb.y - pb.w * 0.5f;
    float x2 = pb.x + pb.z * 0.5f, y2 = pb.y + pb.w * 0.5f;
    float xg1 = tb.x - tb.z * 0.5f, yg1 = tb.y - tb.w * 0.5f;
    float xg2 = tb.x + tb.z * 0.5f, yg2 = tb.y + tb.w * 0.5f;
    float xi1 = fmaxf(x1, xg1), yi1 = fmaxf(y1, yg1);
    float xi2 = fminf(x2, xg2), yi2 = fminf(y2, yg2);
    float inter = fmaxf(xi2 - xi1, 0.f) * fmaxf(yi2 - yi1, 0.f);
    float uni = (x2 - x1) * (y2 - y1) + (xg2 - xg1) * (yg2 - yg1) - inter;
    iou = inter / uni;
    float iou_e = inter / (uni + EPSF);
    float xc1 = fminf(x1, xg1), yc1 = fminf(y1, yg1);
    float xc2 = fmaxf(x2, xg2), yc2 = fmaxf(y2, yg2);
    float dx = xc2 - xc1, dy = yc2 - yc1;
    float diag = dx * dx + dy * dy + EPSF;
    float ex = (x1 + x2 - xg1 - xg2) * 0.5f;
    float ey = (y1 + y2 - yg1 - yg2) * 0.5f;
    float dist = ex * ex + ey * ey;
    diou = 1.f - iou_e + dist / diag;
}

// monotone double -> u64 key, low 9 bits replaced by column index (1..256).
__device__ __forceinline__ unsigned long long dkey(double d, int j) {
    unsigned long long b = (unsigned long long)__double_as_longlong(d);
    b ^= (b >> 63) ? 0xFFFFFFFFFFFFFFFFULL : 0x8000000000000000ULL;
    return (b & ~511ULL) | (unsigned long long)j;
}
__device__ __forceinline__ double unkey(unsigned long long k) {
    unsigned long long b = k & ~511ULL;
    b ^= (b & 0x8000000000000000ULL) ? 0x8000000000000000ULL : 0xFFFFFFFFFFFFFFFFULL;
    return __longlong_as_double((long long)b);
}

#define SEL4I(s, a0, a1, a2, a3) ((s) == 0 ? (a0) : (s) == 1 ? (a1) : (s) == 2 ? (a2) : (a3))
#define SEL4D(s, a0, a1, a2, a3) ((s) == 0 ? (a0) : (s) == 1 ? (a1) : (s) == 2 ? (a2) : (a3))

// Directional DPP min-reduce step on (ka:u64 key, pa:i32 payload).
// old = self, bound_ctrl = false: lanes with no source keep their own value.
// Sequence row_shr:1,2,4,8 then row_bcast:15, row_bcast:31 -> lane 63 = min.
#define RED_DPP(CTRL)                                                                       \
    do {                                                                                    \
        int lo_ = (int)(unsigned int)ka, hi_ = (int)(unsigned int)(ka >> 32);               \
        int nlo_ = __builtin_amdgcn_update_dpp(lo_, lo_, CTRL, 0xF, 0xF, false);            \
        int nhi_ = __builtin_amdgcn_update_dpp(hi_, hi_, CTRL, 0xF, 0xF, false);            \
        int npa_ = __builtin_amdgcn_update_dpp(pa, pa, CTRL, 0xF, 0xF, false);              \
        unsigned long long ok_ = ((unsigned long long)(unsigned int)nhi_ << 32) |           \
                                 (unsigned long long)(unsigned int)nlo_;                    \
        if (ok_ < ka) { ka = ok_; pa = npa_; }                                              \
    } while (0)

// ---------- K0: per-(b,n) BCE log terms ----------
__global__ __launch_bounds__(256) void k_prep(const float* __restrict__ lp,
                                              float* __restrict__ A,
                                              float* __restrict__ C) {
    int idx = blockIdx.x * 256 + threadIdx.x;
    float x = lp[idx];
    float p = 1.f / (1.f + expf(-x));
    A[idx] = -fmaxf(logf(p), -100.f);
    C[idx] = -fmaxf(logf(1.f - p), -100.f);
}

// ---------- K1: batch-constant label_cost and l1_cost [N,M] ----------
__global__ __launch_bounds__(256) void k_nm(const float* __restrict__ A,
                                            const float* __restrict__ C,
                                            const float* __restrict__ bp,
                                            const float* __restrict__ bt,
                                            const float* __restrict__ lt,
                                            float* __restrict__ lc,
                                            float* __restrict__ l1c) {
    int n = blockIdx.x, m = threadIdx.x;
    float sl = 0.f, s1 = 0.f;
    for (int b = 0; b < BB; ++b) {
        float a = A[b * NN + n];
        float c = C[b * NN + n];
        float t = lt[b * MM + m];
        sl += t * a + (1.f - t) * c;
        float4 P = *reinterpret_cast<const float4*>(bp + ((size_t)b * NN + n) * 4);
        float4 T = *reinterpret_cast<const float4*>(bt + ((size_t)b * MM + m) * 4);
        s1 += fabsf(P.x - T.x) + fabsf(P.y - T.y) + fabsf(P.z - T.z) + fabsf(P.w - T.w);
    }
    lc[n * MM + m]  = sl * (1.f / 64.f);
    l1c[n * MM + m] = s1 * (1.f / 256.f);
}

// ---------- K2: full cost tensor [B,N,M] ----------
__global__ __launch_bounds__(256) void k_cost(const float* __restrict__ bp,
                                              const float* __restrict__ bt,
                                              const float* __restrict__ lc,
                                              const float* __restrict__ l1c,
                                              float* __restrict__ cost) {
    int bn = blockIdx.x;
    int b = bn >> 8, n = bn & 255;
    int m = threadIdx.x;
    float4 P = *reinterpret_cast<const float4*>(bp + ((size_t)bn) * 4);
    float4 T = *reinterpret_cast<const float4*>(bt + ((size_t)b * MM + m) * 4);
    float iou, diou;
    iou_diou(P, T, iou, diou);
    cost[((size_t)bn << 8) + m] = diou + lc[(n << 8) + m] + l1c[(n << 8) + m];
}

// ---------- K3: exact LAP (CR + greedy + SSP), one wave per batch ----------
// Lane owns columns 4*lane+q+1 (1-based). Column state in registers; argmin
// via 6 directional DPP steps (pure VALU) + readlane(63) broadcast; first
// ROWS_LDS cost rows served from LDS.
__global__ __launch_bounds__(64) void k_hungarian(const float* __restrict__ cost,
                                                  int* __restrict__ cols) {
    const int b = blockIdx.x;
    const int lane = threadIdx.x;
    const float* Cm = cost + (size_t)b * NN * MM;
    const unsigned long long MAXK = 0xFFFFFFFFFFFFFFFFULL;
    const double INFD = __builtin_inf();

    __shared__ float ldsC[ROWS_LDS * MM];
    __shared__ int jofrow[NN + 1];   // smallest column (1-based) whose argmin is this row
    for (int r = lane; r <= NN; r += 64) jofrow[r] = 0x7fffffff;
    __syncthreads();

    // ---- column reduction: v[j] = min_i c[i][j]; also fill LDS row cache ----
    float cm0 = __builtin_inff(), cm1 = cm0, cm2 = cm0, cm3 = cm0;
    int rm0 = 0, rm1 = 0, rm2 = 0, rm3 = 0;
    #pragma unroll 4
    for (int i = 0; i < NN; ++i) {
        float4 cr = *reinterpret_cast<const float4*>(Cm + (size_t)i * MM + 4 * lane);
        if (i < ROWS_LDS) *reinterpret_cast<float4*>(&ldsC[i * MM + 4 * lane]) = cr;
        if (cr.x < cm0) { cm0 = cr.x; rm0 = i; }
        if (cr.y < cm1) { cm1 = cr.y; rm1 = i; }
        if (cr.z < cm2) { cm2 = cr.z; rm2 = i; }
        if (cr.w < cm3) { cm3 = cr.w; rm3 = i; }
    }
    atomicMin(&jofrow[rm0 + 1], 4 * lane + 1);
    atomicMin(&jofrow[rm1 + 1], 4 * lane + 2);
    atomicMin(&jofrow[rm2 + 1], 4 * lane + 3);
    atomicMin(&jofrow[rm3 + 1], 4 * lane + 4);
    __syncthreads();

    // ---- greedy pre-assignment + register state init ----
    double vj0 = cm0, vj1 = cm1, vj2 = cm2, vj3 = cm3;   // v[j]
    double up0 = 0.0, up1 = 0.0, up2 = 0.0, up3 = 0.0;   // u[p[j]]
    int pj0_ = (jofrow[rm0 + 1] == 4 * lane + 1) ? rm0 + 1 : 0;
    int pj1_ = (jofrow[rm1 + 1] == 4 * lane + 2) ? rm1 + 1 : 0;
    int pj2_ = (jofrow[rm2 + 1] == 4 * lane + 3) ? rm2 + 1 : 0;
    int pj3_ = (jofrow[rm3 + 1] == 4 * lane + 4) ? rm3 + 1 : 0;
    int wy0 = 0, wy1 = 0, wy2 = 0, wy3 = 0;              // way[j]

    // assigned-row bitmasks (wave-uniform)
    unsigned long long am0 = __ballot(jofrow[1 + lane]       != 0x7fffffff);
    unsigned long long am1 = __ballot(jofrow[1 + 64 + lane]  != 0x7fffffff);
    unsigned long long am2 = __ballot(jofrow[1 + 128 + lane] != 0x7fffffff);
    unsigned long long am3 = __ballot(jofrow[1 + 192 + lane] != 0x7fffffff);

    for (int i = 1; i <= NN; ++i) {
        unsigned long long am = (i <= 64) ? am0 : (i <= 128) ? am1 : (i <= 192) ? am2 : am3;
        if ((am >> ((i - 1) & 63)) & 1ULL) continue;   // row pre-assigned

        double u_i = 0.0;
        double mv0 = INFD, mv1 = INFD, mv2 = INFD, mv3 = INFD;
        int used4 = 0;
        int j0 = 0;
        int i0 = i;
        double ui0 = 0.0;

        for (int it = 0; it <= NN; ++it) {
            float4 cr;
            if (i0 - 1 < ROWS_LDS)    // wave-uniform branch
                cr = *reinterpret_cast<const float4*>(&ldsC[(i0 - 1) * MM + 4 * lane]);
            else
                cr = *reinterpret_cast<const float4*>(Cm + (size_t)(i0 - 1) * MM + 4 * lane);

            if (!(used4 & 1)) { double cur = ((double)cr.x - ui0) - vj0; if (cur < mv0) { mv0 = cur; wy0 = j0; } }
            if (!(used4 & 2)) { double cur = ((double)cr.y - ui0) - vj1; if (cur < mv1) { mv1 = cur; wy1 = j0; } }
            if (!(used4 & 4)) { double cur = ((double)cr.z - ui0) - vj2; if (cur < mv2) { mv2 = cur; wy2 = j0; } }
            if (!(used4 & 8)) { double cur = ((double)cr.w - ui0) - vj3; if (cur < mv3) { mv3 = cur; wy3 = j0; } }

            unsigned long long k0 = (used4 & 1) ? MAXK : dkey(mv0, 4 * lane + 1);
            unsigned long long k1 = (used4 & 2) ? MAXK : dkey(mv1, 4 * lane + 2);
            unsigned long long k2 = (used4 & 4) ? MAXK : dkey(mv2, 4 * lane + 3);
            unsigned long long k3 = (used4 & 8) ? MAXK : dkey(mv3, 4 * lane + 4);

            // local payload reduce (value-then-smallest-j via key low bits)
            unsigned long long ka; int pa;
            if (k1 < k0) { ka = k1; pa = pj1_; } else { ka = k0; pa = pj0_; }
            unsigned long long kb; int pb;
            if (k3 < k2) { kb = k3; pb = pj3_; } else { kb = k2; pb = pj2_; }
            if (kb < ka) { ka = kb; pa = pb; }

            // directional DPP reduce into lane 63 (all VALU), then broadcast
            RED_DPP(0x111);   // row_shr:1
            RED_DPP(0x112);   // row_shr:2
            RED_DPP(0x114);   // row_shr:4
            RED_DPP(0x118);   // row_shr:8
            RED_DPP(0x142);   // row_bcast:15
            RED_DPP(0x143);   // row_bcast:31
            {
                unsigned int klo = (unsigned int)__builtin_amdgcn_readlane((int)(unsigned int)ka, 63);
                unsigned int khi = (unsigned int)__builtin_amdgcn_readlane((int)(unsigned int)(ka >> 32), 63);
                pa = __builtin_amdgcn_readlane(pa, 63);
                ka = ((unsigned long long)khi << 32) | klo;
            }

            double delta = unkey(ka);
            int j1 = (int)(ka & 511ULL);

            // winner's u[p[j1]] fetched post-reduce; consumed only after the
            // next row load returns, so this shfl hides under the load.
            int o1 = (j1 - 1) >> 2, s1 = (j1 - 1) & 3;
            double uvq = SEL4D(s1, up0, up1, up2, up3);
            double ua = __shfl(uvq, o1);

            u_i += delta;
            if (used4 & 1) { up0 += delta; vj0 -= delta; } else { mv0 -= delta; }
            if (used4 & 2) { up1 += delta; vj1 -= delta; } else { mv1 -= delta; }
            if (used4 & 4) { up2 += delta; vj2 -= delta; } else { mv2 -= delta; }
            if (used4 & 8) { up3 += delta; vj3 -= delta; } else { mv3 -= delta; }

            j0 = j1;
            if (pa == 0) break;            // reached a free column
            int ci = j1 - 1;
            if ((ci >> 2) == lane) used4 |= 1 << (ci & 3);
            i0 = pa;
            ui0 = ua;
        }

        // ---- augment along way pointers (jj uniform; cross-lane via shfl) ----
        int jj = j0;
        while (jj) {
            int o = (jj - 1) >> 2, s = (jj - 1) & 3;
            int wv = SEL4I(s, wy0, wy1, wy2, wy3);
            int jn = __shfl(wv, o);
            int pn; double un;
            if (jn == 0) { pn = i; un = u_i; }
            else {
                int o2 = (jn - 1) >> 2, s2 = (jn - 1) & 3;
                int pv = SEL4I(s2, pj0_, pj1_, pj2_, pj3_);
                double uv = SEL4D(s2, up0, up1, up2, up3);
                pn = __shfl(pv, o2);
                un = __shfl(uv, o2);
            }
            if (lane == o) {
                if (s == 0)      { pj0_ = pn; up0 = un; }
                else if (s == 1) { pj1_ = pn; up1 = un; }
                else if (s == 2) { pj2_ = pn; up2 = un; }
                else             { pj3_ = pn; up3 = un; }
            }
            jj = jn;
        }
    }

    // col_of_row: cols[p[j]-1] = j-1
    cols[b * NN + (pj0_ - 1)] = 4 * lane + 0;
    cols[b * NN + (pj1_ - 1)] = 4 * lane + 1;
    cols[b * NN + (pj2_ - 1)] = 4 * lane + 2;
    cols[b * NN + (pj3_ - 1)] = 4 * lane + 3;
}

// ---------- K4: matched losses, per-block (batch) partial sums ----------
__global__ __launch_bounds__(256) void k_loss(const float* __restrict__ lp,
                                              const float* __restrict__ bp,
                                              const float* __restrict__ lt,
                                              const float* __restrict__ bt,
                                              const int* __restrict__ cols,
                                              float* __restrict__ partials) {
    int b = blockIdx.x, n = threadIdx.x;
    int col = cols[b * NN + n];
    float x = lp[b * NN + n];
    float pp = 1.f / (1.f + expf(-x));
    float t = lt[b * MM + col];
    float4 P = *reinterpret_cast<const float4*>(bp + ((size_t)b * NN + n) * 4);
    float4 T = *reinterpret_cast<const float4*>(bt + ((size_t)b * MM + col) * 4);
    float w = (t == 1.f) ? 1.f : 0.f;
    float iou, diou;
    iou_diou(P, T, iou, diou);
    float bce = -(t * fmaxf(logf(pp), -100.f) + (1.f - t) * fmaxf(logf(1.f - pp), -100.f));
    float l1 = fabsf(P.x - T.x) + fabsf(P.y - T.y) + fabsf(P.z - T.z) + fabsf(P.w - T.w);

    float v0 = w, v1 = diou * w, v2 = iou * w, v3 = bce, v4 = l1 * w;
    #pragma unroll
    for (int mm = 1; mm < 64; mm <<= 1) {
        v0 += __shfl_xor(v0, mm); v1 += __shfl_xor(v1, mm);
        v2 += __shfl_xor(v2, mm); v3 += __shfl_xor(v3, mm);
        v4 += __shfl_xor(v4, mm);
    }
    __shared__ float red[4][5];
    int wid = n >> 6, lane = n & 63;
    if (lane == 0) { red[wid][0] = v0; red[wid][1] = v1; red[wid][2] = v2; red[wid][3] = v3; red[wid][4] = v4; }
    __syncthreads();
    if (n == 0) {
        float s0 = red[0][0] + red[1][0] + red[2][0] + red[3][0];
        float s1 = red[0][1] + red[1][1] + red[2][1] + red[3][1];
        float s2 = red[0][2] + red[1][2] + red[2][2] + red[3][2];
        float s3 = red[0][3] + red[1][3] + red[2][3] + red[3][3];
        float s4 = red[0][4] + red[1][4] + red[2][4] + red[3][4];
        partials[b * 8 + 0] = s0; partials[b * 8 + 1] = s1; partials[b * 8 + 2] = s2;
        partials[b * 8 + 3] = s3; partials[b * 8 + 4] = s4;
    }
}

// ---------- K5: final scalar combine ----------
__global__ __launch_bounds__(64) void k_final(const float* __restrict__ partials,
                                              float* __restrict__ out) {
    int t = threadIdx.x;
    float v0 = partials[t * 8 + 0], v1 = partials[t * 8 + 1], v2 = partials[t * 8 + 2];
    float v3 = partials[t * 8 + 3], v4 = partials[t * 8 + 4];
    #pragma unroll
    for (int mm = 1; mm < 64; mm <<= 1) {
        v0 += __shfl_xor(v0, mm); v1 += __shfl_xor(v1, mm);
        v2 += __shfl_xor(v2, mm); v3 += __shfl_xor(v3, mm);
        v4 += __shfl_xor(v4, mm);
    }
    if (t == 0) {
        float wsum = v0;
        float diou_loss = v1 / wsum;
        float iou = v2 / wsum;
        float label_loss = v3 * (1.f / (64.f * 256.f));
        float bbox_loss = v4 / (wsum * 4.f);
        out[0] = diou_loss + label_loss + bbox_loss;
        out[1] = iou;
    }
}

extern "C" void kernel_launch(void* const* d_in, const int* in_sizes, int n_in,
                              void* d_out, int out_size, void* d_ws, size_t ws_size,
                              hipStream_t stream) {
    const float* labels_pred   = (const float*)d_in[0];
    const float* bbox_pred     = (const float*)d_in[1];
    const float* labels_target = (const float*)d_in[2];
    const float* bbox_target   = (const float*)d_in[3];
    float* out = (float*)d_out;

    float* A    = (float*)d_ws;
    float* C    = A + BB * NN;
    float* lc   = C + BB * NN;
    float* l1c  = lc + NN * MM;
    float* cost = l1c + NN * MM;
    int*   cols = (int*)(cost + (size_t)BB * NN * MM);
    float* partials = (float*)(cols + BB * NN);

    k_prep<<<BB * NN / 256, 256, 0, stream>>>(labels_pred, A, C);
    k_nm<<<NN, MM, 0, stream>>>(A, C, bbox_pred, bbox_target, labels_target, lc, l1c);
    k_cost<<<BB * NN, MM, 0, stream>>>(bbox_pred, bbox_target, lc, l1c, cost);
    k_hungarian<<<BB, 64, 0, stream>>>(cost, cols);
    k_loss<<<BB, NN, 0, stream>>>(labels_pred, bbox_pred, labels_target, bbox_target, cols, partials);
    k_final<<<1, 64, 0, stream>>>(partials, out);
}

// Round 6
// 3119.306 us; speedup vs baseline: 4.1754x; 1.0278x over previous
//
#include <hip/hip_runtime.h>
#include <math.h>

#define BB 64
#define NN 256
#define MM 256
#define EPSF 1e-7f
#define ROWS_LDS 144   // 144 KB row cache; + jofrow/matches ~2 KB << 160 KB gfx950 LDS

// ---------- helpers ----------

__device__ __forceinline__ void iou_diou(const float4 pb, const float4 tb,
                                         float& iou, float& diou) {
    float x1 = pb.x - pb.z * 0.5f, y1 = pb.y - pb.w * 0.5f;
    float x2 = pb.x + pb.z * 0.5f, y2 = pb.y + pb.w * 0.5f;
    float xg1 = tb.x - tb.z * 0.5f, yg1 = tb.y - tb.w * 0.5f;
    float xg2 = tb.x + tb.z * 0.5f, yg2 = tb.y + tb.w * 0.5f;
    float xi1 = fmaxf(x1, xg1), yi1 = fmaxf(y1, yg1);
    float xi2 = fminf(x2, xg2), yi2 = fminf(y2, yg2);
    float inter = fmaxf(xi2 - xi1, 0.f) * fmaxf(yi2 - yi1, 0.f);
    float uni = (x2 - x1) * (y2 - y1) + (xg2 - xg1) * (yg2 - yg1) - inter;
    iou = inter / uni;
    float iou_e = inter / (uni + EPSF);
    float xc1 = fminf(x1, xg1), yc1 = fminf(y1, yg1);
    float xc2 = fmaxf(x2, xg2), yc2 = fmaxf(y2, yg2);
    float dx = xc2 - xc1, dy = yc2 - yc1;
    float diag = dx * dx + dy * dy + EPSF;
    float ex = (x1 + x2 - xg1 - xg2) * 0.5f;
    float ey = (y1 + y2 - yg1 - yg2) * 0.5f;
    float dist = ex * ex + ey * ey;
    diou = 1.f - iou_e + dist / diag;
}

// monotone double -> u64 key, low 9 bits replaced by column index (1..256).
__device__ __forceinline__ unsigned long long dkey(double d, int j) {
    unsigned long long b = (unsigned long long)__double_as_longlong(d);
    b ^= (b >> 63) ? 0xFFFFFFFFFFFFFFFFULL : 0x8000000000000000ULL;
    return (b & ~511ULL) | (unsigned long long)j;
}
__device__ __forceinline__ double unkey(unsigned long long k) {
    unsigned long long b = k & ~511ULL;
    b ^= (b & 0x8000000000000000ULL) ? 0x8000000000000000ULL : 0xFFFFFFFFFFFFFFFFULL;
    return __longlong_as_double((long long)b);
}

#define SEL4I(s, a0, a1, a2, a3) ((s) == 0 ? (a0) : (s) == 1 ? (a1) : (s) == 2 ? (a2) : (a3))
#define SEL4D(s, a0, a1, a2, a3) ((s) == 0 ? (a0) : (s) == 1 ? (a1) : (s) == 2 ? (a2) : (a3))

// uniform-lane readlane of a double held in a VGPR pair
__device__ __forceinline__ double readlane_d(double v, int lane) {
    unsigned long long b = (unsigned long long)__double_as_longlong(v);
    int lo = __builtin_amdgcn_readlane((int)(unsigned int)b, lane);
    int hi = __builtin_amdgcn_readlane((int)(unsigned int)(b >> 32), lane);
    return __longlong_as_double((long long)(((unsigned long long)(unsigned int)hi << 32) |
                                            (unsigned long long)(unsigned int)lo));
}

// Directional DPP min-reduce step on (ka:u64 key, pa:i32 payload).
// old = self, bound_ctrl = false: lanes with no source keep their own value.
// Sequence row_shr:1,2,4,8 then row_bcast:15, row_bcast:31 -> lane 63 = min.
#define RED_DPP(CTRL)                                                                       \
    do {                                                                                    \
        int lo_ = (int)(unsigned int)ka, hi_ = (int)(unsigned int)(ka >> 32);               \
        int nlo_ = __builtin_amdgcn_update_dpp(lo_, lo_, CTRL, 0xF, 0xF, false);            \
        int nhi_ = __builtin_amdgcn_update_dpp(hi_, hi_, CTRL, 0xF, 0xF, false);            \
        int npa_ = __builtin_amdgcn_update_dpp(pa, pa, CTRL, 0xF, 0xF, false);              \
        unsigned long long ok_ = ((unsigned long long)(unsigned int)nhi_ << 32) |           \
                                 (unsigned long long)(unsigned int)nlo_;                    \
        if (ok_ < ka) { ka = ok_; pa = npa_; }                                              \
    } while (0)

// key-only variant (for plain f64 min, no payload)
#define RED_DPP_K(CTRL)                                                                     \
    do {                                                                                    \
        int lo_ = (int)(unsigned int)ka, hi_ = (int)(unsigned int)(ka >> 32);               \
        int nlo_ = __builtin_amdgcn_update_dpp(lo_, lo_, CTRL, 0xF, 0xF, false);            \
        int nhi_ = __builtin_amdgcn_update_dpp(hi_, hi_, CTRL, 0xF, 0xF, false);            \
        unsigned long long ok_ = ((unsigned long long)(unsigned int)nhi_ << 32) |           \
                                 (unsigned long long)(unsigned int)nlo_;                    \
        if (ok_ < ka) ka = ok_;                                                             \
    } while (0)

// ---------- K0: per-(b,n) BCE log terms ----------
__global__ __launch_bounds__(256) void k_prep(const float* __restrict__ lp,
                                              float* __restrict__ A,
                                              float* __restrict__ C) {
    int idx = blockIdx.x * 256 + threadIdx.x;
    float x = lp[idx];
    float p = 1.f / (1.f + expf(-x));
    A[idx] = -fmaxf(logf(p), -100.f);
    C[idx] = -fmaxf(logf(1.f - p), -100.f);
}

// ---------- K1: batch-constant label_cost and l1_cost [N,M] ----------
__global__ __launch_bounds__(256) void k_nm(const float* __restrict__ A,
                                            const float* __restrict__ C,
                                            const float* __restrict__ bp,
                                            const float* __restrict__ bt,
                                            const float* __restrict__ lt,
                                            float* __restrict__ lc,
                                            float* __restrict__ l1c) {
    int n = blockIdx.x, m = threadIdx.x;
    float sl = 0.f, s1 = 0.f;
    for (int b = 0; b < BB; ++b) {
        float a = A[b * NN + n];
        float c = C[b * NN + n];
        float t = lt[b * MM + m];
        sl += t * a + (1.f - t) * c;
        float4 P = *reinterpret_cast<const float4*>(bp + ((size_t)b * NN + n) * 4);
        float4 T = *reinterpret_cast<const float4*>(bt + ((size_t)b * MM + m) * 4);
        s1 += fabsf(P.x - T.x) + fabsf(P.y - T.y) + fabsf(P.z - T.z) + fabsf(P.w - T.w);
    }
    lc[n * MM + m]  = sl * (1.f / 64.f);
    l1c[n * MM + m] = s1 * (1.f / 256.f);
}

// ---------- K2: full cost tensor [B,N,M] ----------
__global__ __launch_bounds__(256) void k_cost(const float* __restrict__ bp,
                                              const float* __restrict__ bt,
                                              const float* __restrict__ lc,
                                              const float* __restrict__ l1c,
                                              float* __restrict__ cost) {
    int bn = blockIdx.x;
    int b = bn >> 8, n = bn & 255;
    int m = threadIdx.x;
    float4 P = *reinterpret_cast<const float4*>(bp + ((size_t)bn) * 4);
    float4 T = *reinterpret_cast<const float4*>(bt + ((size_t)b * MM + m) * 4);
    float iou, diou;
    iou_diou(P, T, iou, diou);
    cost[((size_t)bn << 8) + m] = diou + lc[(n << 8) + m] + l1c[(n << 8) + m];
}

// ---------- K3: exact LAP (CR + RT + greedy + SSP), one wave per batch ----------
// Lane owns columns 4*lane+q+1 (1-based). Column state in registers; argmin
// via 6 directional DPP steps (pure VALU) + readlane(63); ALL post-reduce
// cross-lane fetches are v_readlane (uniform lane) — no ds_bpermute in loop.
__global__ __launch_bounds__(64) void k_hungarian(const float* __restrict__ cost,
                                                  int* __restrict__ cols) {
    const int b = blockIdx.x;
    const int lane = threadIdx.x;
    const float* Cm = cost + (size_t)b * NN * MM;
    const unsigned long long MAXK = 0xFFFFFFFFFFFFFFFFULL;
    const double INFD = __builtin_inf();

    __shared__ float ldsC[ROWS_LDS * MM];
    __shared__ int jofrow[NN + 1];   // smallest column (1-based) whose argmin is this row
    __shared__ int matches[NN + 1];  // # columns whose argmin is this row
    for (int r = lane; r <= NN; r += 64) { jofrow[r] = 0x7fffffff; matches[r] = 0; }
    __syncthreads();

    // ---- column reduction: v[j] = min_i c[i][j]; also fill LDS row cache ----
    float cm0 = __builtin_inff(), cm1 = cm0, cm2 = cm0, cm3 = cm0;
    int rm0 = 0, rm1 = 0, rm2 = 0, rm3 = 0;
    #pragma unroll 4
    for (int i = 0; i < NN; ++i) {
        float4 cr = *reinterpret_cast<const float4*>(Cm + (size_t)i * MM + 4 * lane);
        if (i < ROWS_LDS) *reinterpret_cast<float4*>(&ldsC[i * MM + 4 * lane]) = cr;
        if (cr.x < cm0) { cm0 = cr.x; rm0 = i; }
        if (cr.y < cm1) { cm1 = cr.y; rm1 = i; }
        if (cr.z < cm2) { cm2 = cr.z; rm2 = i; }
        if (cr.w < cm3) { cm3 = cr.w; rm3 = i; }
    }
    atomicMin(&jofrow[rm0 + 1], 4 * lane + 1);
    atomicMin(&jofrow[rm1 + 1], 4 * lane + 2);
    atomicMin(&jofrow[rm2 + 1], 4 * lane + 3);
    atomicMin(&jofrow[rm3 + 1], 4 * lane + 4);
    atomicAdd(&matches[rm0 + 1], 1);
    atomicAdd(&matches[rm1 + 1], 1);
    atomicAdd(&matches[rm2 + 1], 1);
    atomicAdd(&matches[rm3 + 1], 1);
    __syncthreads();

    // ---- greedy pre-assignment + register state init ----
    double vj0 = cm0, vj1 = cm1, vj2 = cm2, vj3 = cm3;   // v[j]
    double up0 = 0.0, up1 = 0.0, up2 = 0.0, up3 = 0.0;   // u[p[j]]
    int pj0_ = (jofrow[rm0 + 1] == 4 * lane + 1) ? rm0 + 1 : 0;
    int pj1_ = (jofrow[rm1 + 1] == 4 * lane + 2) ? rm1 + 1 : 0;
    int pj2_ = (jofrow[rm2 + 1] == 4 * lane + 3) ? rm2 + 1 : 0;
    int pj3_ = (jofrow[rm3 + 1] == 4 * lane + 4) ? rm3 + 1 : 0;
    int wy0 = 0, wy1 = 0, wy2 = 0, wy3 = 0;              // way[j]

    // assigned-row bitmasks (wave-uniform)
    unsigned long long am0 = __ballot(jofrow[1 + lane]       != 0x7fffffff);
    unsigned long long am1 = __ballot(jofrow[1 + 64 + lane]  != 0x7fffffff);
    unsigned long long am2 = __ballot(jofrow[1 + 128 + lane] != 0x7fffffff);
    unsigned long long am3 = __ballot(jofrow[1 + 192 + lane] != 0x7fffffff);

    // ================= REDUCTION TRANSFER (rows claimed exactly once) =========
    // v[j1] -= min_{j != j1} (c[i][j] - v[j]); u[i] += same. Keeps duals
    // feasible and CS on assigned pairs. (Correctness HW-verified in R3.)
    for (int i = 1; i <= NN; ++i) {
        if (matches[i] != 1) continue;               // uniform branch
        int j1 = jofrow[i];                          // uniform
        int o = (j1 - 1) >> 2, s = (j1 - 1) & 3;
        float4 cr;
        if (i - 1 < ROWS_LDS)
            cr = *reinterpret_cast<const float4*>(&ldsC[(i - 1) * MM + 4 * lane]);
        else
            cr = *reinterpret_cast<const float4*>(Cm + (size_t)(i - 1) * MM + 4 * lane);
        double h0 = (double)cr.x - vj0;
        double h1 = (double)cr.y - vj1;
        double h2 = (double)cr.z - vj2;
        double h3 = (double)cr.w - vj3;
        if (lane == o) {
            if (s == 0) h0 = INFD; else if (s == 1) h1 = INFD;
            else if (s == 2) h2 = INFD; else h3 = INFD;
        }
        // all h >= 0: raw IEEE bits are monotone as u64 — exact min, no index
        double hm = fmin(fmin(h0, h1), fmin(h2, h3));
        unsigned long long ka = (unsigned long long)__double_as_longlong(hm);
        RED_DPP_K(0x111); RED_DPP_K(0x112); RED_DPP_K(0x114); RED_DPP_K(0x118);
        RED_DPP_K(0x142); RED_DPP_K(0x143);
        double m = readlane_d(__longlong_as_double((long long)ka), 63);
        if (lane == o) {
            if (s == 0)      { vj0 -= m; up0 += m; }
            else if (s == 1) { vj1 -= m; up1 += m; }
            else if (s == 2) { vj2 -= m; up2 += m; }
            else             { vj3 -= m; up3 += m; }
        }
    }

    // ================= SSP (Dijkstra) for free rows =================
    for (int i = 1; i <= NN; ++i) {
        unsigned long long am = (i <= 64) ? am0 : (i <= 128) ? am1 : (i <= 192) ? am2 : am3;
        if ((am >> ((i - 1) & 63)) & 1ULL) continue;   // row pre-assigned

        double u_i = 0.0;
        double mv0 = INFD, mv1 = INFD, mv2 = INFD, mv3 = INFD;
        int used4 = 0;
        int j0 = 0;
        int i0 = i;
        double ui0 = 0.0;

        for (int it = 0; it <= NN; ++it) {
            float4 cr;
            if (i0 - 1 < ROWS_LDS)    // wave-uniform branch
                cr = *reinterpret_cast<const float4*>(&ldsC[(i0 - 1) * MM + 4 * lane]);
            else
                cr = *reinterpret_cast<const float4*>(Cm + (size_t)(i0 - 1) * MM + 4 * lane);

            if (!(used4 & 1)) { double cur = ((double)cr.x - ui0) - vj0; if (cur < mv0) { mv0 = cur; wy0 = j0; } }
            if (!(used4 & 2)) { double cur = ((double)cr.y - ui0) - vj1; if (cur < mv1) { mv1 = cur; wy1 = j0; } }
            if (!(used4 & 4)) { double cur = ((double)cr.z - ui0) - vj2; if (cur < mv2) { mv2 = cur; wy2 = j0; } }
            if (!(used4 & 8)) { double cur = ((double)cr.w - ui0) - vj3; if (cur < mv3) { mv3 = cur; wy3 = j0; } }

            unsigned long long k0 = (used4 & 1) ? MAXK : dkey(mv0, 4 * lane + 1);
            unsigned long long k1 = (used4 & 2) ? MAXK : dkey(mv1, 4 * lane + 2);
            unsigned long long k2 = (used4 & 4) ? MAXK : dkey(mv2, 4 * lane + 3);
            unsigned long long k3 = (used4 & 8) ? MAXK : dkey(mv3, 4 * lane + 4);

            // local payload reduce (value-then-smallest-j via key low bits)
            unsigned long long ka; int pa;
            if (k1 < k0) { ka = k1; pa = pj1_; } else { ka = k0; pa = pj0_; }
            unsigned long long kb; int pb;
            if (k3 < k2) { kb = k3; pb = pj3_; } else { kb = k2; pb = pj2_; }
            if (kb < ka) { ka = kb; pa = pb; }

            // directional DPP reduce into lane 63 (all VALU), then broadcast
            RED_DPP(0x111);   // row_shr:1
            RED_DPP(0x112);   // row_shr:2
            RED_DPP(0x114);   // row_shr:4
            RED_DPP(0x118);   // row_shr:8
            RED_DPP(0x142);   // row_bcast:15
            RED_DPP(0x143);   // row_bcast:31
            {
                unsigned int klo = (unsigned int)__builtin_amdgcn_readlane((int)(unsigned int)ka, 63);
                unsigned int khi = (unsigned int)__builtin_amdgcn_readlane((int)(unsigned int)(ka >> 32), 63);
                pa = __builtin_amdgcn_readlane(pa, 63);
                ka = ((unsigned long long)khi << 32) | klo;
            }

            double delta = unkey(ka);
            int j1 = (int)(ka & 511ULL);

            // winner's u[p[j1]] via readlane (uniform lane) — no LDS-pipe op
            int o1 = (j1 - 1) >> 2, s1 = (j1 - 1) & 3;
            double uvq = SEL4D(s1, up0, up1, up2, up3);
            double ua = readlane_d(uvq, o1);

            u_i += delta;
            if (used4 & 1) { up0 += delta; vj0 -= delta; } else { mv0 -= delta; }
            if (used4 & 2) { up1 += delta; vj1 -= delta; } else { mv1 -= delta; }
            if (used4 & 4) { up2 += delta; vj2 -= delta; } else { mv2 -= delta; }
            if (used4 & 8) { up3 += delta; vj3 -= delta; } else { mv3 -= delta; }

            j0 = j1;
            if (pa == 0) break;            // reached a free column
            int ci = j1 - 1;
            if ((ci >> 2) == lane) used4 |= 1 << (ci & 3);
            i0 = pa;
            ui0 = ua;
        }

        // ---- augment along way pointers (all indices uniform -> readlane) ----
        int jj = j0;
        while (jj) {
            int o = (jj - 1) >> 2, s = (jj - 1) & 3;
            int wv = SEL4I(s, wy0, wy1, wy2, wy3);
            int jn = __builtin_amdgcn_readlane(wv, o);
            int pn; double un;
            if (jn == 0) { pn = i; un = u_i; }
            else {
                int o2 = (jn - 1) >> 2, s2 = (jn - 1) & 3;
                int pv = SEL4I(s2, pj0_, pj1_, pj2_, pj3_);
                double uv = SEL4D(s2, up0, up1, up2, up3);
                pn = __builtin_amdgcn_readlane(pv, o2);
                un = readlane_d(uv, o2);
            }
            if (lane == o) {
                if (s == 0)      { pj0_ = pn; up0 = un; }
                else if (s == 1) { pj1_ = pn; up1 = un; }
                else if (s == 2) { pj2_ = pn; up2 = un; }
                else             { pj3_ = pn; up3 = un; }
            }
            jj = jn;
        }
    }

    // col_of_row: cols[p[j]-1] = j-1
    cols[b * NN + (pj0_ - 1)] = 4 * lane + 0;
    cols[b * NN + (pj1_ - 1)] = 4 * lane + 1;
    cols[b * NN + (pj2_ - 1)] = 4 * lane + 2;
    cols[b * NN + (pj3_ - 1)] = 4 * lane + 3;
}

// ---------- K4: matched losses, per-block (batch) partial sums ----------
__global__ __launch_bounds__(256) void k_loss(const float* __restrict__ lp,
                                              const float* __restrict__ bp,
                                              const float* __restrict__ lt,
                                              const float* __restrict__ bt,
                                              const int* __restrict__ cols,
                                              float* __restrict__ partials) {
    int b = blockIdx.x, n = threadIdx.x;
    int col = cols[b * NN + n];
    float x = lp[b * NN + n];
    float pp = 1.f / (1.f + expf(-x));
    float t = lt[b * MM + col];
    float4 P = *reinterpret_cast<const float4*>(bp + ((size_t)b * NN + n) * 4);
    float4 T = *reinterpret_cast<const float4*>(bt + ((size_t)b * MM + col) * 4);
    float w = (t == 1.f) ? 1.f : 0.f;
    float iou, diou;
    iou_diou(P, T, iou, diou);
    float bce = -(t * fmaxf(logf(pp), -100.f) + (1.f - t) * fmaxf(logf(1.f - pp), -100.f));
    float l1 = fabsf(P.x - T.x) + fabsf(P.y - T.y) + fabsf(P.z - T.z) + fabsf(P.w - T.w);

    float v0 = w, v1 = diou * w, v2 = iou * w, v3 = bce, v4 = l1 * w;
    #pragma unroll
    for (int mm = 1; mm < 64; mm <<= 1) {
        v0 += __shfl_xor(v0, mm); v1 += __shfl_xor(v1, mm);
        v2 += __shfl_xor(v2, mm); v3 += __shfl_xor(v3, mm);
        v4 += __shfl_xor(v4, mm);
    }
    __shared__ float red[4][5];
    int wid = n >> 6, lane = n & 63;
    if (lane == 0) { red[wid][0] = v0; red[wid][1] = v1; red[wid][2] = v2; red[wid][3] = v3; red[wid][4] = v4; }
    __syncthreads();
    if (n == 0) {
        float s0 = red[0][0] + red[1][0] + red[2][0] + red[3][0];
        float s1 = red[0][1] + red[1][1] + red[2][1] + red[3][1];
        float s2 = red[0][2] + red[1][2] + red[2][2] + red[3][2];
        float s3 = red[0][3] + red[1][3] + red[2][3] + red[3][3];
        float s4 = red[0][4] + red[1][4] + red[2][4] + red[3][4];
        partials[b * 8 + 0] = s0; partials[b * 8 + 1] = s1; partials[b * 8 + 2] = s2;
        partials[b * 8 + 3] = s3; partials[b * 8 + 4] = s4;
    }
}

// ---------- K5: final scalar combine ----------
__global__ __launch_bounds__(64) void k_final(const float* __restrict__ partials,
                                              float* __restrict__ out) {
    int t = threadIdx.x;
    float v0 = partials[t * 8 + 0], v1 = partials[t * 8 + 1], v2 = partials[t * 8 + 2];
    float v3 = partials[t * 8 + 3], v4 = partials[t * 8 + 4];
    #pragma unroll
    for (int mm = 1; mm < 64; mm <<= 1) {
        v0 += __shfl_xor(v0, mm); v1 += __shfl_xor(v1, mm);
        v2 += __shfl_xor(v2, mm); v3 += __shfl_xor(v3, mm);
        v4 += __shfl_xor(v4, mm);
    }
    if (t == 0) {
        float wsum = v0;
        float diou_loss = v1 / wsum;
        float iou = v2 / wsum;
        float label_loss = v3 * (1.f / (64.f * 256.f));
        float bbox_loss = v4 / (wsum * 4.f);
        out[0] = diou_loss + label_loss + bbox_loss;
        out[1] = iou;
    }
}

extern "C" void kernel_launch(void* const* d_in, const int* in_sizes, int n_in,
                              void* d_out, int out_size, void* d_ws, size_t ws_size,
                              hipStream_t stream) {
    const float* labels_pred   = (const float*)d_in[0];
    const float* bbox_pred     = (const float*)d_in[1];
    const float* labels_target = (const float*)d_in[2];
    const float* bbox_target   = (const float*)d_in[3];
    float* out = (float*)d_out;

    float* A    = (float*)d_ws;
    float* C    = A + BB * NN;
    float* lc   = C + BB * NN;
    float* l1c  = lc + NN * MM;
    float* cost = l1c + NN * MM;
    int*   cols = (int*)(cost + (size_t)BB * NN * MM);
    float* partials = (float*)(cols + BB * NN);

    k_prep<<<BB * NN / 256, 256, 0, stream>>>(labels_pred, A, C);
    k_nm<<<NN, MM, 0, stream>>>(A, C, bbox_pred, bbox_target, labels_target, lc, l1c);
    k_cost<<<BB * NN, MM, 0, stream>>>(bbox_pred, bbox_target, lc, l1c, cost);
    k_hungarian<<<BB, 64, 0, stream>>>(cost, cols);
    k_loss<<<BB, NN, 0, stream>>>(labels_pred, bbox_pred, labels_target, bbox_target, cols, partials);
    k_final<<<1, 64, 0, stream>>>(partials, out);
}

// Round 7
// 2811.271 us; speedup vs baseline: 4.6329x; 1.1096x over previous
//
#include <hip/hip_runtime.h>
#include <math.h>

#define BB 64
#define NN 256
#define MM 256
#define EPSF 1e-7f
#define ROWS_LDS 157   // 157 KB row cache + jofrow/matches ~2 KB = 159.8 KB <= 160 KB

// ---------- helpers ----------

__device__ __forceinline__ void iou_diou(const float4 pb, const float4 tb,
                                         float& iou, float& diou) {
    float x1 = pb.x - pb.z * 0.5f, y1 = pb.y - pb.w * 0.5f;
    float x2 = pb.x + pb.z * 0.5f, y2 = pb.y + pb.w * 0.5f;
    float xg1 = tb.x - tb.z * 0.5f, yg1 = tb.y - tb.w * 0.5f;
    float xg2 = tb.x + tb.z * 0.5f, yg2 = tb.y + tb.w * 0.5f;
    float xi1 = fmaxf(x1, xg1), yi1 = fmaxf(y1, yg1);
    float xi2 = fminf(x2, xg2), yi2 = fminf(y2, yg2);
    float inter = fmaxf(xi2 - xi1, 0.f) * fmaxf(yi2 - yi1, 0.f);
    float uni = (x2 - x1) * (y2 - y1) + (xg2 - xg1) * (yg2 - yg1) - inter;
    iou = inter / uni;
    float iou_e = inter / (uni + EPSF);
    float xc1 = fminf(x1, xg1), yc1 = fminf(y1, yg1);
    float xc2 = fmaxf(x2, xg2), yc2 = fmaxf(y2, yg2);
    float dx = xc2 - xc1, dy = yc2 - yc1;
    float diag = dx * dx + dy * dy + EPSF;
    float ex = (x1 + x2 - xg1 - xg2) * 0.5f;
    float ey = (y1 + y2 - yg1 - yg2) * 0.5f;
    float dist = ex * ex + ey * ey;
    diou = 1.f - iou_e + dist / diag;
}

// monotone double -> u64 key, low 9 bits replaced by column index (1..256).
__device__ __forceinline__ unsigned long long dkey(double d, int j) {
    unsigned long long b = (unsigned long long)__double_as_longlong(d);
    b ^= (b >> 63) ? 0xFFFFFFFFFFFFFFFFULL : 0x8000000000000000ULL;
    return (b & ~511ULL) | (unsigned long long)j;
}
__device__ __forceinline__ double unkey(unsigned long long k) {
    unsigned long long b = k & ~511ULL;
    b ^= (b & 0x8000000000000000ULL) ? 0x8000000000000000ULL : 0xFFFFFFFFFFFFFFFFULL;
    return __longlong_as_double((long long)b);
}

#define SEL4I(s, a0, a1, a2, a3) ((s) == 0 ? (a0) : (s) == 1 ? (a1) : (s) == 2 ? (a2) : (a3))
#define SEL4D(s, a0, a1, a2, a3) ((s) == 0 ? (a0) : (s) == 1 ? (a1) : (s) == 2 ? (a2) : (a3))

// uniform-lane readlane of a double held in a VGPR pair
__device__ __forceinline__ double readlane_d(double v, int lane) {
    unsigned long long b = (unsigned long long)__double_as_longlong(v);
    int lo = __builtin_amdgcn_readlane((int)(unsigned int)b, lane);
    int hi = __builtin_amdgcn_readlane((int)(unsigned int)(b >> 32), lane);
    return __longlong_as_double((long long)(((unsigned long long)(unsigned int)hi << 32) |
                                            (unsigned long long)(unsigned int)lo));
}

// Directional DPP min-reduce step, KEY ONLY (u64). old=self, bound_ctrl=false.
// Sequence row_shr:1,2,4,8 then row_bcast:15, row_bcast:31 -> lane 63 = min.
#define RED_DPP_K(CTRL)                                                                     \
    do {                                                                                    \
        int lo_ = (int)(unsigned int)ka, hi_ = (int)(unsigned int)(ka >> 32);               \
        int nlo_ = __builtin_amdgcn_update_dpp(lo_, lo_, CTRL, 0xF, 0xF, false);            \
        int nhi_ = __builtin_amdgcn_update_dpp(hi_, hi_, CTRL, 0xF, 0xF, false);            \
        unsigned long long ok_ = ((unsigned long long)(unsigned int)nhi_ << 32) |           \
                                 (unsigned long long)(unsigned int)nlo_;                    \
        if (ok_ < ka) ka = ok_;                                                             \
    } while (0)

#define RED_ALL()                                                                           \
    do {                                                                                    \
        RED_DPP_K(0x111); RED_DPP_K(0x112); RED_DPP_K(0x114); RED_DPP_K(0x118);             \
        RED_DPP_K(0x142); RED_DPP_K(0x143);                                                 \
        unsigned int klo_ = (unsigned int)__builtin_amdgcn_readlane((int)(unsigned int)ka, 63); \
        unsigned int khi_ = (unsigned int)__builtin_amdgcn_readlane((int)(unsigned int)(ka >> 32), 63); \
        ka = ((unsigned long long)khi_ << 32) | klo_;                                       \
    } while (0)

// ---------- K0: per-(b,n) BCE log terms ----------
__global__ __launch_bounds__(256) void k_prep(const float* __restrict__ lp,
                                              float* __restrict__ A,
                                              float* __restrict__ C) {
    int idx = blockIdx.x * 256 + threadIdx.x;
    float x = lp[idx];
    float p = 1.f / (1.f + expf(-x));
    A[idx] = -fmaxf(logf(p), -100.f);
    C[idx] = -fmaxf(logf(1.f - p), -100.f);
}

// ---------- K1: batch-constant label_cost and l1_cost [N,M] ----------
__global__ __launch_bounds__(256) void k_nm(const float* __restrict__ A,
                                            const float* __restrict__ C,
                                            const float* __restrict__ bp,
                                            const float* __restrict__ bt,
                                            const float* __restrict__ lt,
                                            float* __restrict__ lc,
                                            float* __restrict__ l1c) {
    int n = blockIdx.x, m = threadIdx.x;
    float sl = 0.f, s1 = 0.f;
    for (int b = 0; b < BB; ++b) {
        float a = A[b * NN + n];
        float c = C[b * NN + n];
        float t = lt[b * MM + m];
        sl += t * a + (1.f - t) * c;
        float4 P = *reinterpret_cast<const float4*>(bp + ((size_t)b * NN + n) * 4);
        float4 T = *reinterpret_cast<const float4*>(bt + ((size_t)b * MM + m) * 4);
        s1 += fabsf(P.x - T.x) + fabsf(P.y - T.y) + fabsf(P.z - T.z) + fabsf(P.w - T.w);
    }
    lc[n * MM + m]  = sl * (1.f / 64.f);
    l1c[n * MM + m] = s1 * (1.f / 256.f);
}

// ---------- K2: full cost tensor [B,N,M] ----------
__global__ __launch_bounds__(256) void k_cost(const float* __restrict__ bp,
                                              const float* __restrict__ bt,
                                              const float* __restrict__ lc,
                                              const float* __restrict__ l1c,
                                              float* __restrict__ cost) {
    int bn = blockIdx.x;
    int b = bn >> 8, n = bn & 255;
    int m = threadIdx.x;
    float4 P = *reinterpret_cast<const float4*>(bp + ((size_t)bn) * 4);
    float4 T = *reinterpret_cast<const float4*>(bt + ((size_t)b * MM + m) * 4);
    float iou, diou;
    iou_diou(P, T, iou, diou);
    cost[((size_t)bn << 8) + m] = diou + lc[(n << 8) + m] + l1c[(n << 8) + m];
}

// ---------- K3: exact LAP (CR + RT + greedy2 + SSP), one wave per batch ----------
__global__ __launch_bounds__(64) void k_hungarian(const float* __restrict__ cost,
                                                  int* __restrict__ cols) {
    const int b = blockIdx.x;
    const int lane = threadIdx.x;
    const float* Cm = cost + (size_t)b * NN * MM;
    const unsigned long long MAXK = 0xFFFFFFFFFFFFFFFFULL;
    const double INFD = __builtin_inf();

    __shared__ float ldsC[ROWS_LDS * MM];
    __shared__ int jofrow[NN + 1];   // smallest column (1-based) whose argmin is this row
    __shared__ int matches[NN + 1];  // # columns whose argmin is this row
    for (int r = lane; r <= NN; r += 64) { jofrow[r] = 0x7fffffff; matches[r] = 0; }
    __syncthreads();

    // ---- column reduction: v[j] = min_i c[i][j]; also fill LDS row cache ----
    float cm0 = __builtin_inff(), cm1 = cm0, cm2 = cm0, cm3 = cm0;
    int rm0 = 0, rm1 = 0, rm2 = 0, rm3 = 0;
    #pragma unroll 4
    for (int i = 0; i < NN; ++i) {
        float4 cr = *reinterpret_cast<const float4*>(Cm + (size_t)i * MM + 4 * lane);
        if (i < ROWS_LDS) *reinterpret_cast<float4*>(&ldsC[i * MM + 4 * lane]) = cr;
        if (cr.x < cm0) { cm0 = cr.x; rm0 = i; }
        if (cr.y < cm1) { cm1 = cr.y; rm1 = i; }
        if (cr.z < cm2) { cm2 = cr.z; rm2 = i; }
        if (cr.w < cm3) { cm3 = cr.w; rm3 = i; }
    }
    atomicMin(&jofrow[rm0 + 1], 4 * lane + 1);
    atomicMin(&jofrow[rm1 + 1], 4 * lane + 2);
    atomicMin(&jofrow[rm2 + 1], 4 * lane + 3);
    atomicMin(&jofrow[rm3 + 1], 4 * lane + 4);
    atomicAdd(&matches[rm0 + 1], 1);
    atomicAdd(&matches[rm1 + 1], 1);
    atomicAdd(&matches[rm2 + 1], 1);
    atomicAdd(&matches[rm3 + 1], 1);
    __syncthreads();

    // ---- greedy pre-assignment + register state init ----
    double vj0 = cm0, vj1 = cm1, vj2 = cm2, vj3 = cm3;   // v[j]
    double up0 = 0.0, up1 = 0.0, up2 = 0.0, up3 = 0.0;   // u[p[j]]
    int pj0_ = (jofrow[rm0 + 1] == 4 * lane + 1) ? rm0 + 1 : 0;
    int pj1_ = (jofrow[rm1 + 1] == 4 * lane + 2) ? rm1 + 1 : 0;
    int pj2_ = (jofrow[rm2 + 1] == 4 * lane + 3) ? rm2 + 1 : 0;
    int pj3_ = (jofrow[rm3 + 1] == 4 * lane + 4) ? rm3 + 1 : 0;
    int wy0 = 0, wy1 = 0, wy2 = 0, wy3 = 0;              // way[j]

    // assigned-row bitmasks (wave-uniform)
    unsigned long long am0 = __ballot(jofrow[1 + lane]       != 0x7fffffff);
    unsigned long long am1 = __ballot(jofrow[1 + 64 + lane]  != 0x7fffffff);
    unsigned long long am2 = __ballot(jofrow[1 + 128 + lane] != 0x7fffffff);
    unsigned long long am3 = __ballot(jofrow[1 + 192 + lane] != 0x7fffffff);

    // ================= REDUCTION TRANSFER (rows claimed exactly once) =========
    for (int i = 1; i <= NN; ++i) {
        if (matches[i] != 1) continue;               // uniform branch
        int j1 = jofrow[i];                          // uniform
        int o = (j1 - 1) >> 2, s = (j1 - 1) & 3;
        float4 cr;
        if (i - 1 < ROWS_LDS)
            cr = *reinterpret_cast<const float4*>(&ldsC[(i - 1) * MM + 4 * lane]);
        else
            cr = *reinterpret_cast<const float4*>(Cm + (size_t)(i - 1) * MM + 4 * lane);
        double h0 = (double)cr.x - vj0;
        double h1 = (double)cr.y - vj1;
        double h2 = (double)cr.z - vj2;
        double h3 = (double)cr.w - vj3;
        if (lane == o) {
            if (s == 0) h0 = INFD; else if (s == 1) h1 = INFD;
            else if (s == 2) h2 = INFD; else h3 = INFD;
        }
        // all h >= 0: raw IEEE bits are monotone as u64 — exact min, no index
        double hm = fmin(fmin(h0, h1), fmin(h2, h3));
        unsigned long long ka = (unsigned long long)__double_as_longlong(hm);
        RED_ALL();
        double m = __longlong_as_double((long long)ka);
        if (lane == o) {
            if (s == 0)      { vj0 -= m; up0 += m; }
            else if (s == 1) { vj1 -= m; up1 += m; }
            else if (s == 2) { vj2 -= m; up2 += m; }
            else             { vj3 -= m; up3 += m; }
        }
    }

    // ================= GREEDY-2: assign free rows whose argmin column is free ==
    // u_i = full-row min of reduced cost (feasible); CS exact at (i, j1).
    // Non-displacing -> single bounded pass, cannot thrash.
    for (int i = 1; i <= NN; ++i) {
        unsigned long long amv = (i <= 64) ? am0 : (i <= 128) ? am1 : (i <= 192) ? am2 : am3;
        if ((amv >> ((i - 1) & 63)) & 1ULL) continue;
        float4 cr;
        if (i - 1 < ROWS_LDS)
            cr = *reinterpret_cast<const float4*>(&ldsC[(i - 1) * MM + 4 * lane]);
        else
            cr = *reinterpret_cast<const float4*>(Cm + (size_t)(i - 1) * MM + 4 * lane);
        double h0 = (double)cr.x - vj0;
        double h1 = (double)cr.y - vj1;
        double h2 = (double)cr.z - vj2;
        double h3 = (double)cr.w - vj3;
        unsigned long long k0 = dkey(h0, 4 * lane + 1);
        unsigned long long k1 = dkey(h1, 4 * lane + 2);
        unsigned long long k2 = dkey(h2, 4 * lane + 3);
        unsigned long long k3 = dkey(h3, 4 * lane + 4);
        unsigned long long ea = k1 < k0 ? k1 : k0;
        unsigned long long eb = k3 < k2 ? k3 : k2;
        unsigned long long ka = eb < ea ? eb : ea;
        RED_ALL();
        int j1 = (int)(ka & 511ULL);
        int o1 = (j1 - 1) >> 2, s1 = (j1 - 1) & 3;
        int pcur = __builtin_amdgcn_readlane(SEL4I(s1, pj0_, pj1_, pj2_, pj3_), o1);
        if (pcur == 0) {                  // argmin column free -> take it
            double u_i = unkey(ka);
            if (lane == o1) {
                if (s1 == 0)      { pj0_ = i; up0 = u_i; }
                else if (s1 == 1) { pj1_ = i; up1 = u_i; }
                else if (s1 == 2) { pj2_ = i; up2 = u_i; }
                else              { pj3_ = i; up3 = u_i; }
            }
            unsigned long long bit = 1ULL << ((i - 1) & 63);
            if (i <= 64) am0 |= bit; else if (i <= 128) am1 |= bit;
            else if (i <= 192) am2 |= bit; else am3 |= bit;
        }
    }

    // ================= SSP (Dijkstra) for remaining free rows =================
    for (int i = 1; i <= NN; ++i) {
        unsigned long long amv = (i <= 64) ? am0 : (i <= 128) ? am1 : (i <= 192) ? am2 : am3;
        if ((amv >> ((i - 1) & 63)) & 1ULL) continue;   // row assigned

        double u_i = 0.0;
        double mv0 = INFD, mv1 = INFD, mv2 = INFD, mv3 = INFD;
        int used4 = 0;
        int j0 = 0;
        int i0 = i;
        double ui0 = 0.0;

        for (int it = 0; it <= NN; ++it) {
            // off-critical-path: fold ui0 into v (1 sub on the load chain)
            double uv0 = ui0 + vj0, uv1 = ui0 + vj1, uv2 = ui0 + vj2, uv3 = ui0 + vj3;
            float4 cr;
            if (i0 - 1 < ROWS_LDS)    // wave-uniform branch
                cr = *reinterpret_cast<const float4*>(&ldsC[(i0 - 1) * MM + 4 * lane]);
            else
                cr = *reinterpret_cast<const float4*>(Cm + (size_t)(i0 - 1) * MM + 4 * lane);

            if (!(used4 & 1)) { double cur = (double)cr.x - uv0; if (cur < mv0) { mv0 = cur; wy0 = j0; } }
            if (!(used4 & 2)) { double cur = (double)cr.y - uv1; if (cur < mv1) { mv1 = cur; wy1 = j0; } }
            if (!(used4 & 4)) { double cur = (double)cr.z - uv2; if (cur < mv2) { mv2 = cur; wy2 = j0; } }
            if (!(used4 & 8)) { double cur = (double)cr.w - uv3; if (cur < mv3) { mv3 = cur; wy3 = j0; } }

            unsigned long long k0 = (used4 & 1) ? MAXK : dkey(mv0, 4 * lane + 1);
            unsigned long long k1 = (used4 & 2) ? MAXK : dkey(mv1, 4 * lane + 2);
            unsigned long long k2 = (used4 & 4) ? MAXK : dkey(mv2, 4 * lane + 3);
            unsigned long long k3 = (used4 & 8) ? MAXK : dkey(mv3, 4 * lane + 4);

            unsigned long long ea = k1 < k0 ? k1 : k0;
            unsigned long long eb = k3 < k2 ? k3 : k2;
            unsigned long long ka = eb < ea ? eb : ea;

            // key-only DPP reduce (no payload), winner broadcast from lane 63
            RED_ALL();

            double delta = unkey(ka);
            int j1 = (int)(ka & 511ULL);
            int o1 = (j1 - 1) >> 2, s1 = (j1 - 1) & 3;
            // post-reduce uniform-lane fetches (SALU-side, no LDS pipe)
            int pa = __builtin_amdgcn_readlane(SEL4I(s1, pj0_, pj1_, pj2_, pj3_), o1);
            double ua = readlane_d(SEL4D(s1, up0, up1, up2, up3), o1);

            u_i += delta;
            if (used4 & 1) { up0 += delta; vj0 -= delta; } else { mv0 -= delta; }
            if (used4 & 2) { up1 += delta; vj1 -= delta; } else { mv1 -= delta; }
            if (used4 & 4) { up2 += delta; vj2 -= delta; } else { mv2 -= delta; }
            if (used4 & 8) { up3 += delta; vj3 -= delta; } else { mv3 -= delta; }

            j0 = j1;
            if (pa == 0) break;            // reached a free column
            int ci = j1 - 1;
            if ((ci >> 2) == lane) used4 |= 1 << (ci & 3);
            i0 = pa;
            ui0 = ua;
        }

        // ---- augment along way pointers (all indices uniform -> readlane) ----
        int jj = j0;
        while (jj) {
            int o = (jj - 1) >> 2, s = (jj - 1) & 3;
            int wv = SEL4I(s, wy0, wy1, wy2, wy3);
            int jn = __builtin_amdgcn_readlane(wv, o);
            int pn; double un;
            if (jn == 0) { pn = i; un = u_i; }
            else {
                int o2 = (jn - 1) >> 2, s2 = (jn - 1) & 3;
                int pv = SEL4I(s2, pj0_, pj1_, pj2_, pj3_);
                double uv = SEL4D(s2, up0, up1, up2, up3);
                pn = __builtin_amdgcn_readlane(pv, o2);
                un = readlane_d(uv, o2);
            }
            if (lane == o) {
                if (s == 0)      { pj0_ = pn; up0 = un; }
                else if (s == 1) { pj1_ = pn; up1 = un; }
                else if (s == 2) { pj2_ = pn; up2 = un; }
                else             { pj3_ = pn; up3 = un; }
            }
            jj = jn;
        }
    }

    // col_of_row: cols[p[j]-1] = j-1
    cols[b * NN + (pj0_ - 1)] = 4 * lane + 0;
    cols[b * NN + (pj1_ - 1)] = 4 * lane + 1;
    cols[b * NN + (pj2_ - 1)] = 4 * lane + 2;
    cols[b * NN + (pj3_ - 1)] = 4 * lane + 3;
}

// ---------- K4: matched losses, per-block (batch) partial sums ----------
__global__ __launch_bounds__(256) void k_loss(const float* __restrict__ lp,
                                              const float* __restrict__ bp,
                                              const float* __restrict__ lt,
                                              const float* __restrict__ bt,
                                              const int* __restrict__ cols,
                                              float* __restrict__ partials) {
    int b = blockIdx.x, n = threadIdx.x;
    int col = cols[b * NN + n];
    float x = lp[b * NN + n];
    float pp = 1.f / (1.f + expf(-x));
    float t = lt[b * MM + col];
    float4 P = *reinterpret_cast<const float4*>(bp + ((size_t)b * NN + n) * 4);
    float4 T = *reinterpret_cast<const float4*>(bt + ((size_t)b * MM + col) * 4);
    float w = (t == 1.f) ? 1.f : 0.f;
    float iou, diou;
    iou_diou(P, T, iou, diou);
    float bce = -(t * fmaxf(logf(pp), -100.f) + (1.f - t) * fmaxf(logf(1.f - pp), -100.f));
    float l1 = fabsf(P.x - T.x) + fabsf(P.y - T.y) + fabsf(P.z - T.z) + fabsf(P.w - T.w);

    float v0 = w, v1 = diou * w, v2 = iou * w, v3 = bce, v4 = l1 * w;
    #pragma unroll
    for (int mm = 1; mm < 64; mm <<= 1) {
        v0 += __shfl_xor(v0, mm); v1 += __shfl_xor(v1, mm);
        v2 += __shfl_xor(v2, mm); v3 += __shfl_xor(v3, mm);
        v4 += __shfl_xor(v4, mm);
    }
    __shared__ float red[4][5];
    int wid = n >> 6, lane = n & 63;
    if (lane == 0) { red[wid][0] = v0; red[wid][1] = v1; red[wid][2] = v2; red[wid][3] = v3; red[wid][4] = v4; }
    __syncthreads();
    if (n == 0) {
        float s0 = red[0][0] + red[1][0] + red[2][0] + red[3][0];
        float s1 = red[0][1] + red[1][1] + red[2][1] + red[3][1];
        float s2 = red[0][2] + red[1][2] + red[2][2] + red[3][2];
        float s3 = red[0][3] + red[1][3] + red[2][3] + red[3][3];
        float s4 = red[0][4] + red[1][4] + red[2][4] + red[3][4];
        partials[b * 8 + 0] = s0; partials[b * 8 + 1] = s1; partials[b * 8 + 2] = s2;
        partials[b * 8 + 3] = s3; partials[b * 8 + 4] = s4;
    }
}

// ---------- K5: final scalar combine ----------
__global__ __launch_bounds__(64) void k_final(const float* __restrict__ partials,
                                              float* __restrict__ out) {
    int t = threadIdx.x;
    float v0 = partials[t * 8 + 0], v1 = partials[t * 8 + 1], v2 = partials[t * 8 + 2];
    float v3 = partials[t * 8 + 3], v4 = partials[t * 8 + 4];
    #pragma unroll
    for (int mm = 1; mm < 64; mm <<= 1) {
        v0 += __shfl_xor(v0, mm); v1 += __shfl_xor(v1, mm);
        v2 += __shfl_xor(v2, mm); v3 += __shfl_xor(v3, mm);
        v4 += __shfl_xor(v4, mm);
    }
    if (t == 0) {
        float wsum = v0;
        float diou_loss = v1 / wsum;
        float iou = v2 / wsum;
        float label_loss = v3 * (1.f / (64.f * 256.f));
        float bbox_loss = v4 / (wsum * 4.f);
        out[0] = diou_loss + label_loss + bbox_loss;
        out[1] = iou;
    }
}

extern "C" void kernel_launch(void* const* d_in, const int* in_sizes, int n_in,
                              void* d_out, int out_size, void* d_ws, size_t ws_size,
                              hipStream_t stream) {
    const float* labels_pred   = (const float*)d_in[0];
    const float* bbox_pred     = (const float*)d_in[1];
    const float* labels_target = (const float*)d_in[2];
    const float* bbox_target   = (const float*)d_in[3];
    float* out = (float*)d_out;

    float* A    = (float*)d_ws;
    float* C    = A + BB * NN;
    float* lc   = C + BB * NN;
    float* l1c  = lc + NN * MM;
    float* cost = l1c + NN * MM;
    int*   cols = (int*)(cost + (size_t)BB * NN * MM);
    float* partials = (float*)(cols + BB * NN);

    k_prep<<<BB * NN / 256, 256, 0, stream>>>(labels_pred, A, C);
    k_nm<<<NN, MM, 0, stream>>>(A, C, bbox_pred, bbox_target, labels_target, lc, l1c);
    k_cost<<<BB * NN, MM, 0, stream>>>(bbox_pred, bbox_target, lc, l1c, cost);
    k_hungarian<<<BB, 64, 0, stream>>>(cost, cols);
    k_loss<<<BB, NN, 0, stream>>>(labels_pred, bbox_pred, labels_target, bbox_target, cols, partials);
    k_final<<<1, 64, 0, stream>>>(partials, out);
}

// Round 8
// 2455.318 us; speedup vs baseline: 5.3045x; 1.1450x over previous
//
#include <hip/hip_runtime.h>
#include <math.h>

#define BB 64
#define NN 256
#define MM 256
#define EPSF 1e-7f
#define ROWS_LDS 156   // 156 KB row cache + jofrow/matches/u0 ~3 KB = 159 KB <= 160 KB

// ---------- helpers ----------

__device__ __forceinline__ void iou_diou(const float4 pb, const float4 tb,
                                         float& iou, float& diou) {
    float x1 = pb.x - pb.z * 0.5f, y1 = pb.y - pb.w * 0.5f;
    float x2 = pb.x + pb.z * 0.5f, y2 = pb.y + pb.w * 0.5f;
    float xg1 = tb.x - tb.z * 0.5f, yg1 = tb.y - tb.w * 0.5f;
    float xg2 = tb.x + tb.z * 0.5f, yg2 = tb.y + tb.w * 0.5f;
    float xi1 = fmaxf(x1, xg1), yi1 = fmaxf(y1, yg1);
    float xi2 = fminf(x2, xg2), yi2 = fminf(y2, yg2);
    float inter = fmaxf(xi2 - xi1, 0.f) * fmaxf(yi2 - yi1, 0.f);
    float uni = (x2 - x1) * (y2 - y1) + (xg2 - xg1) * (yg2 - yg1) - inter;
    iou = inter / uni;
    float iou_e = inter / (uni + EPSF);
    float xc1 = fminf(x1, xg1), yc1 = fminf(y1, yg1);
    float xc2 = fmaxf(x2, xg2), yc2 = fmaxf(y2, yg2);
    float dx = xc2 - xc1, dy = yc2 - yc1;
    float diag = dx * dx + dy * dy + EPSF;
    float ex = (x1 + x2 - xg1 - xg2) * 0.5f;
    float ey = (y1 + y2 - yg1 - yg2) * 0.5f;
    float dist = ex * ex + ey * ey;
    diou = 1.f - iou_e + dist / diag;
}

// monotone double -> u64 key, low 9 bits replaced by column index (1..256).
__device__ __forceinline__ unsigned long long dkey(double d, int j) {
    unsigned long long b = (unsigned long long)__double_as_longlong(d);
    b ^= (b >> 63) ? 0xFFFFFFFFFFFFFFFFULL : 0x8000000000000000ULL;
    return (b & ~511ULL) | (unsigned long long)j;
}
__device__ __forceinline__ double unkey(unsigned long long k) {
    unsigned long long b = k & ~511ULL;
    b ^= (b & 0x8000000000000000ULL) ? 0x8000000000000000ULL : 0xFFFFFFFFFFFFFFFFULL;
    return __longlong_as_double((long long)b);
}

#define SEL4I(s, a0, a1, a2, a3) ((s) == 0 ? (a0) : (s) == 1 ? (a1) : (s) == 2 ? (a2) : (a3))
#define SEL4D(s, a0, a1, a2, a3) ((s) == 0 ? (a0) : (s) == 1 ? (a1) : (s) == 2 ? (a2) : (a3))

// uniform-lane readlane of a double held in a VGPR pair
__device__ __forceinline__ double readlane_d(double v, int lane) {
    unsigned long long b = (unsigned long long)__double_as_longlong(v);
    int lo = __builtin_amdgcn_readlane((int)(unsigned int)b, lane);
    int hi = __builtin_amdgcn_readlane((int)(unsigned int)(b >> 32), lane);
    return __longlong_as_double((long long)(((unsigned long long)(unsigned int)hi << 32) |
                                            (unsigned long long)(unsigned int)lo));
}

// Directional DPP min-reduce step, KEY ONLY (u64). old=self, bound_ctrl=false.
// Sequence row_shr:1,2,4,8 then row_bcast:15, row_bcast:31 -> lane 63 = min.
#define RED_DPP_K(CTRL)                                                                     \
    do {                                                                                    \
        int lo_ = (int)(unsigned int)ka, hi_ = (int)(unsigned int)(ka >> 32);               \
        int nlo_ = __builtin_amdgcn_update_dpp(lo_, lo_, CTRL, 0xF, 0xF, false);            \
        int nhi_ = __builtin_amdgcn_update_dpp(hi_, hi_, CTRL, 0xF, 0xF, false);            \
        unsigned long long ok_ = ((unsigned long long)(unsigned int)nhi_ << 32) |           \
                                 (unsigned long long)(unsigned int)nlo_;                    \
        if (ok_ < ka) ka = ok_;                                                             \
    } while (0)

#define RED_ALL()                                                                           \
    do {                                                                                    \
        RED_DPP_K(0x111); RED_DPP_K(0x112); RED_DPP_K(0x114); RED_DPP_K(0x118);             \
        RED_DPP_K(0x142); RED_DPP_K(0x143);                                                 \
        unsigned int klo_ = (unsigned int)__builtin_amdgcn_readlane((int)(unsigned int)ka, 63); \
        unsigned int khi_ = (unsigned int)__builtin_amdgcn_readlane((int)(unsigned int)(ka >> 32), 63); \
        ka = ((unsigned long long)khi_ << 32) | klo_;                                       \
    } while (0)

// u32 min reduce (for nonneg f32 bits — monotone). Result broadcast from lane 63.
#define RED_U32_STEP(CTRL)                                                                  \
    do {                                                                                    \
        unsigned int n_ = (unsigned int)__builtin_amdgcn_update_dpp((int)kb, (int)kb, CTRL, 0xF, 0xF, false); \
        if (n_ < kb) kb = n_;                                                               \
    } while (0)
#define RED_U32_ALL()                                                                       \
    do {                                                                                    \
        RED_U32_STEP(0x111); RED_U32_STEP(0x112); RED_U32_STEP(0x114); RED_U32_STEP(0x118); \
        RED_U32_STEP(0x142); RED_U32_STEP(0x143);                                           \
        kb = (unsigned int)__builtin_amdgcn_readlane((int)kb, 63);                          \
    } while (0)

// ---------- K0: per-(b,n) BCE log terms ----------
__global__ __launch_bounds__(256) void k_prep(const float* __restrict__ lp,
                                              float* __restrict__ A,
                                              float* __restrict__ C) {
    int idx = blockIdx.x * 256 + threadIdx.x;
    float x = lp[idx];
    float p = 1.f / (1.f + expf(-x));
    A[idx] = -fmaxf(logf(p), -100.f);
    C[idx] = -fmaxf(logf(1.f - p), -100.f);
}

// ---------- K1: batch-constant label_cost and l1_cost [N,M] ----------
__global__ __launch_bounds__(256) void k_nm(const float* __restrict__ A,
                                            const float* __restrict__ C,
                                            const float* __restrict__ bp,
                                            const float* __restrict__ bt,
                                            const float* __restrict__ lt,
                                            float* __restrict__ lc,
                                            float* __restrict__ l1c) {
    int n = blockIdx.x, m = threadIdx.x;
    float sl = 0.f, s1 = 0.f;
    for (int b = 0; b < BB; ++b) {
        float a = A[b * NN + n];
        float c = C[b * NN + n];
        float t = lt[b * MM + m];
        sl += t * a + (1.f - t) * c;
        float4 P = *reinterpret_cast<const float4*>(bp + ((size_t)b * NN + n) * 4);
        float4 T = *reinterpret_cast<const float4*>(bt + ((size_t)b * MM + m) * 4);
        s1 += fabsf(P.x - T.x) + fabsf(P.y - T.y) + fabsf(P.z - T.z) + fabsf(P.w - T.w);
    }
    lc[n * MM + m]  = sl * (1.f / 64.f);
    l1c[n * MM + m] = s1 * (1.f / 256.f);
}

// ---------- K2: full cost tensor [B,N,M] ----------
__global__ __launch_bounds__(256) void k_cost(const float* __restrict__ bp,
                                              const float* __restrict__ bt,
                                              const float* __restrict__ lc,
                                              const float* __restrict__ l1c,
                                              float* __restrict__ cost) {
    int bn = blockIdx.x;
    int b = bn >> 8, n = bn & 255;
    int m = threadIdx.x;
    float4 P = *reinterpret_cast<const float4*>(bp + ((size_t)bn) * 4);
    float4 T = *reinterpret_cast<const float4*>(bt + ((size_t)b * MM + m) * 4);
    float iou, diou;
    iou_diou(P, T, iou, diou);
    cost[((size_t)bn << 8) + m] = diou + lc[(n << 8) + m] + l1c[(n << 8) + m];
}

// ---------- K3: exact LAP (rowred + colred + RT + greedy2 + SSP), 1 wave/batch --
__global__ __launch_bounds__(64) void k_hungarian(const float* __restrict__ cost,
                                                  int* __restrict__ cols) {
    const int b = blockIdx.x;
    const int lane = threadIdx.x;
    const float* Cm = cost + (size_t)b * NN * MM;
    const unsigned long long MAXK = 0xFFFFFFFFFFFFFFFFULL;
    const double INFD = __builtin_inf();

    __shared__ float ldsC[ROWS_LDS * MM];
    __shared__ float ldsU[NN];       // row duals u0[i] (exact f32 row minima)
    __shared__ int jofrow[NN + 1];   // smallest column (1-based) whose argmin is this row
    __shared__ int matches[NN + 1];  // # columns whose argmin is this row
    for (int r = lane; r <= NN; r += 64) { jofrow[r] = 0x7fffffff; matches[r] = 0; }
    __syncthreads();

    // ---- fused row reduction + column reduction on (c - u0) + LDS stash ----
    // u0[i] = min_j c[i][j] (exact f32); cm[j] = min_i ((double)c - (double)u0[i])
    // (each diff is exact in f64 since both operands are f32-representable).
    double cm0 = INFD, cm1 = INFD, cm2 = INFD, cm3 = INFD;
    int rm0 = 0, rm1 = 0, rm2 = 0, rm3 = 0;
    for (int i = 0; i < NN; ++i) {
        float4 cr = *reinterpret_cast<const float4*>(Cm + (size_t)i * MM + 4 * lane);
        if (i < ROWS_LDS) *reinterpret_cast<float4*>(&ldsC[i * MM + 4 * lane]) = cr;
        // row min (all costs >= 0 -> f32 bits monotone as u32)
        float rl = fminf(fminf(cr.x, cr.y), fminf(cr.z, cr.w));
        unsigned int kb = __float_as_uint(rl);
        RED_U32_ALL();
        float u0i = __uint_as_float(kb);
        if (lane == 0) ldsU[i] = u0i;
        double du = (double)u0i;
        double h0 = (double)cr.x - du;
        double h1 = (double)cr.y - du;
        double h2 = (double)cr.z - du;
        double h3 = (double)cr.w - du;
        if (h0 < cm0) { cm0 = h0; rm0 = i; }
        if (h1 < cm1) { cm1 = h1; rm1 = i; }
        if (h2 < cm2) { cm2 = h2; rm2 = i; }
        if (h3 < cm3) { cm3 = h3; rm3 = i; }
    }
    atomicMin(&jofrow[rm0 + 1], 4 * lane + 1);
    atomicMin(&jofrow[rm1 + 1], 4 * lane + 2);
    atomicMin(&jofrow[rm2 + 1], 4 * lane + 3);
    atomicMin(&jofrow[rm3 + 1], 4 * lane + 4);
    atomicAdd(&matches[rm0 + 1], 1);
    atomicAdd(&matches[rm1 + 1], 1);
    atomicAdd(&matches[rm2 + 1], 1);
    atomicAdd(&matches[rm3 + 1], 1);
    __syncthreads();

    // ---- greedy pre-assignment + register state init ----
    double vj0 = cm0, vj1 = cm1, vj2 = cm2, vj3 = cm3;   // v[j]
    int pj0_ = (jofrow[rm0 + 1] == 4 * lane + 1) ? rm0 + 1 : 0;
    int pj1_ = (jofrow[rm1 + 1] == 4 * lane + 2) ? rm1 + 1 : 0;
    int pj2_ = (jofrow[rm2 + 1] == 4 * lane + 3) ? rm2 + 1 : 0;
    int pj3_ = (jofrow[rm3 + 1] == 4 * lane + 4) ? rm3 + 1 : 0;
    // u[p[j]] = u0[claimed row] (CS equality: u0 + v = c at the argmin)
    double up0 = pj0_ ? (double)ldsU[pj0_ - 1] : 0.0;
    double up1 = pj1_ ? (double)ldsU[pj1_ - 1] : 0.0;
    double up2 = pj2_ ? (double)ldsU[pj2_ - 1] : 0.0;
    double up3 = pj3_ ? (double)ldsU[pj3_ - 1] : 0.0;
    int wy0 = 0, wy1 = 0, wy2 = 0, wy3 = 0;              // way[j]

    // assigned-row bitmasks (wave-uniform)
    unsigned long long am0 = __ballot(jofrow[1 + lane]       != 0x7fffffff);
    unsigned long long am1 = __ballot(jofrow[1 + 64 + lane]  != 0x7fffffff);
    unsigned long long am2 = __ballot(jofrow[1 + 128 + lane] != 0x7fffffff);
    unsigned long long am3 = __ballot(jofrow[1 + 192 + lane] != 0x7fffffff);

    // ================= REDUCTION TRANSFER (rows claimed exactly once) =========
    for (int i = 1; i <= NN; ++i) {
        if (matches[i] != 1) continue;               // uniform branch
        int j1 = jofrow[i];                          // uniform
        int o = (j1 - 1) >> 2, s = (j1 - 1) & 3;
        float4 cr;
        if (i - 1 < ROWS_LDS)
            cr = *reinterpret_cast<const float4*>(&ldsC[(i - 1) * MM + 4 * lane]);
        else
            cr = *reinterpret_cast<const float4*>(Cm + (size_t)(i - 1) * MM + 4 * lane);
        double du = (double)ldsU[i - 1];
        double h0 = ((double)cr.x - du) - vj0;
        double h1 = ((double)cr.y - du) - vj1;
        double h2 = ((double)cr.z - du) - vj2;
        double h3 = ((double)cr.w - du) - vj3;
        if (lane == o) {
            if (s == 0) h0 = INFD; else if (s == 1) h1 = INFD;
            else if (s == 2) h2 = INFD; else h3 = INFD;
        }
        // all h >= 0: raw IEEE bits are monotone as u64 — exact min, no index
        double hm = fmin(fmin(h0, h1), fmin(h2, h3));
        unsigned long long ka = (unsigned long long)__double_as_longlong(hm);
        RED_ALL();
        double m = __longlong_as_double((long long)ka);
        if (lane == o) {
            if (s == 0)      { vj0 -= m; up0 += m; }
            else if (s == 1) { vj1 -= m; up1 += m; }
            else if (s == 2) { vj2 -= m; up2 += m; }
            else             { vj3 -= m; up3 += m; }
        }
    }

    // ================= GREEDY-2: assign free rows whose argmin column is free ==
    for (int i = 1; i <= NN; ++i) {
        unsigned long long amv = (i <= 64) ? am0 : (i <= 128) ? am1 : (i <= 192) ? am2 : am3;
        if ((amv >> ((i - 1) & 63)) & 1ULL) continue;
        float4 cr;
        if (i - 1 < ROWS_LDS)
            cr = *reinterpret_cast<const float4*>(&ldsC[(i - 1) * MM + 4 * lane]);
        else
            cr = *reinterpret_cast<const float4*>(Cm + (size_t)(i - 1) * MM + 4 * lane);
        double du = (double)ldsU[i - 1];
        double h0 = ((double)cr.x - du) - vj0;
        double h1 = ((double)cr.y - du) - vj1;
        double h2 = ((double)cr.z - du) - vj2;
        double h3 = ((double)cr.w - du) - vj3;
        unsigned long long k0 = dkey(h0, 4 * lane + 1);
        unsigned long long k1 = dkey(h1, 4 * lane + 2);
        unsigned long long k2 = dkey(h2, 4 * lane + 3);
        unsigned long long k3 = dkey(h3, 4 * lane + 4);
        unsigned long long ea = k1 < k0 ? k1 : k0;
        unsigned long long eb = k3 < k2 ? k3 : k2;
        unsigned long long ka = eb < ea ? eb : ea;
        RED_ALL();
        int j1 = (int)(ka & 511ULL);
        int o1 = (j1 - 1) >> 2, s1 = (j1 - 1) & 3;
        int pcur = __builtin_amdgcn_readlane(SEL4I(s1, pj0_, pj1_, pj2_, pj3_), o1);
        if (pcur == 0) {                  // argmin column free -> take it
            double u_i = du + unkey(ka);  // u[i] = u0[i] + rowmin of reduced cost
            if (lane == o1) {
                if (s1 == 0)      { pj0_ = i; up0 = u_i; }
                else if (s1 == 1) { pj1_ = i; up1 = u_i; }
                else if (s1 == 2) { pj2_ = i; up2 = u_i; }
                else              { pj3_ = i; up3 = u_i; }
            }
            unsigned long long bit = 1ULL << ((i - 1) & 63);
            if (i <= 64) am0 |= bit; else if (i <= 128) am1 |= bit;
            else if (i <= 192) am2 |= bit; else am3 |= bit;
        }
    }

    // ================= SSP (Dijkstra) for remaining free rows =================
    for (int i = 1; i <= NN; ++i) {
        unsigned long long amv = (i <= 64) ? am0 : (i <= 128) ? am1 : (i <= 192) ? am2 : am3;
        if ((amv >> ((i - 1) & 63)) & 1ULL) continue;   // row assigned

        double u_i = (double)ldsU[i - 1];   // u[i] starts at row dual
        double mv0 = INFD, mv1 = INFD, mv2 = INFD, mv3 = INFD;
        int used4 = 0;
        int j0 = 0;
        int i0 = i;
        double ui0 = u_i;

        for (int it = 0; it <= NN; ++it) {
            // off-critical-path: fold ui0 into v (1 sub on the load chain)
            double uv0 = ui0 + vj0, uv1 = ui0 + vj1, uv2 = ui0 + vj2, uv3 = ui0 + vj3;
            float4 cr;
            if (i0 - 1 < ROWS_LDS)    // wave-uniform branch
                cr = *reinterpret_cast<const float4*>(&ldsC[(i0 - 1) * MM + 4 * lane]);
            else
                cr = *reinterpret_cast<const float4*>(Cm + (size_t)(i0 - 1) * MM + 4 * lane);

            if (!(used4 & 1)) { double cur = (double)cr.x - uv0; if (cur < mv0) { mv0 = cur; wy0 = j0; } }
            if (!(used4 & 2)) { double cur = (double)cr.y - uv1; if (cur < mv1) { mv1 = cur; wy1 = j0; } }
            if (!(used4 & 4)) { double cur = (double)cr.z - uv2; if (cur < mv2) { mv2 = cur; wy2 = j0; } }
            if (!(used4 & 8)) { double cur = (double)cr.w - uv3; if (cur < mv3) { mv3 = cur; wy3 = j0; } }

            unsigned long long k0 = (used4 & 1) ? MAXK : dkey(mv0, 4 * lane + 1);
            unsigned long long k1 = (used4 & 2) ? MAXK : dkey(mv1, 4 * lane + 2);
            unsigned long long k2 = (used4 & 4) ? MAXK : dkey(mv2, 4 * lane + 3);
            unsigned long long k3 = (used4 & 8) ? MAXK : dkey(mv3, 4 * lane + 4);

            unsigned long long ea = k1 < k0 ? k1 : k0;
            unsigned long long eb = k3 < k2 ? k3 : k2;
            unsigned long long ka = eb < ea ? eb : ea;

            // key-only DPP reduce (no payload), winner broadcast from lane 63
            RED_ALL();

            double delta = unkey(ka);
            int j1 = (int)(ka & 511ULL);
            int o1 = (j1 - 1) >> 2, s1 = (j1 - 1) & 3;
            // post-reduce uniform-lane fetches (SALU-side, no LDS pipe)
            int pa = __builtin_amdgcn_readlane(SEL4I(s1, pj0_, pj1_, pj2_, pj3_), o1);
            double ua = readlane_d(SEL4D(s1, up0, up1, up2, up3), o1);

            u_i += delta;
            if (used4 & 1) { up0 += delta; vj0 -= delta; } else { mv0 -= delta; }
            if (used4 & 2) { up1 += delta; vj1 -= delta; } else { mv1 -= delta; }
            if (used4 & 4) { up2 += delta; vj2 -= delta; } else { mv2 -= delta; }
            if (used4 & 8) { up3 += delta; vj3 -= delta; } else { mv3 -= delta; }

            j0 = j1;
            if (pa == 0) break;            // reached a free column
            int ci = j1 - 1;
            if ((ci >> 2) == lane) used4 |= 1 << (ci & 3);
            i0 = pa;
            ui0 = ua;
        }

        // ---- augment along way pointers (all indices uniform -> readlane) ----
        int jj = j0;
        while (jj) {
            int o = (jj - 1) >> 2, s = (jj - 1) & 3;
            int wv = SEL4I(s, wy0, wy1, wy2, wy3);
            int jn = __builtin_amdgcn_readlane(wv, o);
            int pn; double un;
            if (jn == 0) { pn = i; un = u_i; }
            else {
                int o2 = (jn - 1) >> 2, s2 = (jn - 1) & 3;
                int pv = SEL4I(s2, pj0_, pj1_, pj2_, pj3_);
                double uv = SEL4D(s2, up0, up1, up2, up3);
                pn = __builtin_amdgcn_readlane(pv, o2);
                un = readlane_d(uv, o2);
            }
            if (lane == o) {
                if (s == 0)      { pj0_ = pn; up0 = un; }
                else if (s == 1) { pj1_ = pn; up1 = un; }
                else if (s == 2) { pj2_ = pn; up2 = un; }
                else             { pj3_ = pn; up3 = un; }
            }
            jj = jn;
        }
    }

    // col_of_row: cols[p[j]-1] = j-1
    cols[b * NN + (pj0_ - 1)] = 4 * lane + 0;
    cols[b * NN + (pj1_ - 1)] = 4 * lane + 1;
    cols[b * NN + (pj2_ - 1)] = 4 * lane + 2;
    cols[b * NN + (pj3_ - 1)] = 4 * lane + 3;
}

// ---------- K4: matched losses, per-block (batch) partial sums ----------
__global__ __launch_bounds__(256) void k_loss(const float* __restrict__ lp,
                                              const float* __restrict__ bp,
                                              const float* __restrict__ lt,
                                              const float* __restrict__ bt,
                                              const int* __restrict__ cols,
                                              float* __restrict__ partials) {
    int b = blockIdx.x, n = threadIdx.x;
    int col = cols[b * NN + n];
    float x = lp[b * NN + n];
    float pp = 1.f / (1.f + expf(-x));
    float t = lt[b * MM + col];
    float4 P = *reinterpret_cast<const float4*>(bp + ((size_t)b * NN + n) * 4);
    float4 T = *reinterpret_cast<const float4*>(bt + ((size_t)b * MM + col) * 4);
    float w = (t == 1.f) ? 1.f : 0.f;
    float iou, diou;
    iou_diou(P, T, iou, diou);
    float bce = -(t * fmaxf(logf(pp), -100.f) + (1.f - t) * fmaxf(logf(1.f - pp), -100.f));
    float l1 = fabsf(P.x - T.x) + fabsf(P.y - T.y) + fabsf(P.z - T.z) + fabsf(P.w - T.w);

    float v0 = w, v1 = diou * w, v2 = iou * w, v3 = bce, v4 = l1 * w;
    #pragma unroll
    for (int mm = 1; mm < 64; mm <<= 1) {
        v0 += __shfl_xor(v0, mm); v1 += __shfl_xor(v1, mm);
        v2 += __shfl_xor(v2, mm); v3 += __shfl_xor(v3, mm);
        v4 += __shfl_xor(v4, mm);
    }
    __shared__ float red[4][5];
    int wid = n >> 6, lane = n & 63;
    if (lane == 0) { red[wid][0] = v0; red[wid][1] = v1; red[wid][2] = v2; red[wid][3] = v3; red[wid][4] = v4; }
    __syncthreads();
    if (n == 0) {
        float s0 = red[0][0] + red[1][0] + red[2][0] + red[3][0];
        float s1 = red[0][1] + red[1][1] + red[2][1] + red[3][1];
        float s2 = red[0][2] + red[1][2] + red[2][2] + red[3][2];
        float s3 = red[0][3] + red[1][3] + red[2][3] + red[3][3];
        float s4 = red[0][4] + red[1][4] + red[2][4] + red[3][4];
        partials[b * 8 + 0] = s0; partials[b * 8 + 1] = s1; partials[b * 8 + 2] = s2;
        partials[b * 8 + 3] = s3; partials[b * 8 + 4] = s4;
    }
}

// ---------- K5: final scalar combine ----------
__global__ __launch_bounds__(64) void k_final(const float* __restrict__ partials,
                                              float* __restrict__ out) {
    int t = threadIdx.x;
    float v0 = partials[t * 8 + 0], v1 = partials[t * 8 + 1], v2 = partials[t * 8 + 2];
    float v3 = partials[t * 8 + 3], v4 = partials[t * 8 + 4];
    #pragma unroll
    for (int mm = 1; mm < 64; mm <<= 1) {
        v0 += __shfl_xor(v0, mm); v1 += __shfl_xor(v1, mm);
        v2 += __shfl_xor(v2, mm); v3 += __shfl_xor(v3, mm);
        v4 += __shfl_xor(v4, mm);
    }
    if (t == 0) {
        float wsum = v0;
        float diou_loss = v1 / wsum;
        float iou = v2 / wsum;
        float label_loss = v3 * (1.f / (64.f * 256.f));
        float bbox_loss = v4 / (wsum * 4.f);
        out[0] = diou_loss + label_loss + bbox_loss;
        out[1] = iou;
    }
}

extern "C" void kernel_launch(void* const* d_in, const int* in_sizes, int n_in,
                              void* d_out, int out_size, void* d_ws, size_t ws_size,
                              hipStream_t stream) {
    const float* labels_pred   = (const float*)d_in[0];
    const float* bbox_pred     = (const float*)d_in[1];
    const float* labels_target = (const float*)d_in[2];
    const float* bbox_target   = (const float*)d_in[3];
    float* out = (float*)d_out;

    float* A    = (float*)d_ws;
    float* C    = A + BB * NN;
    float* lc   = C + BB * NN;
    float* l1c  = lc + NN * MM;
    float* cost = l1c + NN * MM;
    int*   cols = (int*)(cost + (size_t)BB * NN * MM);
    float* partials = (float*)(cols + BB * NN);

    k_prep<<<BB * NN / 256, 256, 0, stream>>>(labels_pred, A, C);
    k_nm<<<NN, MM, 0, stream>>>(A, C, bbox_pred, bbox_target, labels_target, lc, l1c);
    k_cost<<<BB * NN, MM, 0, stream>>>(bbox_pred, bbox_target, lc, l1c, cost);
    k_hungarian<<<BB, 64, 0, stream>>>(cost, cols);
    k_loss<<<BB, NN, 0, stream>>>(labels_pred, bbox_pred, labels_target, bbox_target, cols, partials);
    k_final<<<1, 64, 0, stream>>>(partials, out);
}